// Round 1
// baseline (664.341 us; speedup 1.0000x reference)
//
#include <hip/hip_runtime.h>

#define N_NODES 131072
#define NE      2097152
#define CIN     64
#define HID     64
#define H2X     128   // 2*HID
#define NODESG  128   // nodes per graph
#define NGRAPH  1024
#define NCLS    4

// ---------------- preprocessing ----------------

__global__ void k_edge_deg(const int* __restrict__ dst, const float* __restrict__ ew,
                           float* __restrict__ deg, int* __restrict__ counts) {
    int e = blockIdx.x * blockDim.x + threadIdx.x;
    if (e < NE) {
        int d = dst[e];
        atomicAdd(&deg[d], ew[e]);
        atomicAdd(&counts[d], 1);
    }
}

__global__ void k_dis(const float* __restrict__ deg, float* __restrict__ dis) {
    int n = blockIdx.x * blockDim.x + threadIdx.x;
    if (n < N_NODES) dis[n] = rsqrtf(deg[n] + 1.0f);  // +1 = self-loop weight
}

// exclusive scan of counts -> rowptr, chunk = 512/block
__global__ void k_scan1(const int* __restrict__ counts, int* __restrict__ rowptr,
                        int* __restrict__ partial) {
    __shared__ int sd[256];
    int t = threadIdx.x;
    int base = blockIdx.x * 512;
    int c0 = counts[base + 2*t];
    int c1 = counts[base + 2*t + 1];
    int loc = c0 + c1;
    sd[t] = loc;
    __syncthreads();
    for (int off = 1; off < 256; off <<= 1) {
        int v = (t >= off) ? sd[t - off] : 0;
        __syncthreads();
        sd[t] += v;
        __syncthreads();
    }
    int excl = sd[t] - loc;
    rowptr[base + 2*t]     = excl;
    rowptr[base + 2*t + 1] = excl + c0;
    if (t == 255) partial[blockIdx.x] = sd[t];
}

__global__ void k_scan2(int* __restrict__ partial) {
    __shared__ int sd[256];
    int t = threadIdx.x;
    int v0 = partial[t];
    sd[t] = v0;
    __syncthreads();
    for (int off = 1; off < 256; off <<= 1) {
        int v = (t >= off) ? sd[t - off] : 0;
        __syncthreads();
        sd[t] += v;
        __syncthreads();
    }
    partial[t] = sd[t] - v0;  // exclusive
}

__global__ void k_scan3(int* __restrict__ rowptr, const int* __restrict__ partial) {
    int i = blockIdx.x * blockDim.x + threadIdx.x;
    if (i < N_NODES) rowptr[i] += partial[i >> 9];
}

__global__ void k_edge_csr(const int* __restrict__ src, const int* __restrict__ dst,
                           const float* __restrict__ ew, const float* __restrict__ dis,
                           const int* __restrict__ rowptr, int* __restrict__ cursor,
                           int2* __restrict__ csr) {
    int e = blockIdx.x * blockDim.x + threadIdx.x;
    if (e < NE) {
        int s = src[e], d = dst[e];
        float nrm = dis[s] * ew[e] * dis[d];
        int pos = atomicAdd(&cursor[d], 1);
        csr[rowptr[d] + pos] = make_int2(s, __float_as_int(nrm));
    }
}

// ---------------- layer 1: h1 = relu( (A_hat x) @ W1 + b1 ) ----------------
// block = 256 thr (4 waves), 32 nodes/block (8 per wave, lane = channel)

__global__ __launch_bounds__(256) void k_layer1(
        const float* __restrict__ x, const int2* __restrict__ csr,
        const int* __restrict__ rowptr, const int* __restrict__ counts,
        const float* __restrict__ dis, const float* __restrict__ W1,
        const float* __restrict__ b1, float* __restrict__ h1) {
    __shared__ float sW[CIN * H2X];           // 32 KB
    __shared__ float sb[H2X];
    __shared__ float sagg[32][CIN + 1];       // pad for bank spread
    int tid = threadIdx.x;

    const float4* W4 = (const float4*)W1;
    float4* sW4 = (float4*)sW;
    #pragma unroll
    for (int k = 0; k < 8; ++k) sW4[tid + 256*k] = W4[tid + 256*k];
    if (tid < H2X) sb[tid] = b1[tid];

    int wave = tid >> 6, lane = tid & 63;
    int n0 = blockIdx.x * 32;

    for (int i = 0; i < 8; ++i) {
        int m = wave * 8 + i;
        int n = n0 + m;
        float dn = dis[n];
        int rs = rowptr[n], cnt = counts[n];
        float acc = x[(size_t)n * CIN + lane] * (dn * dn);   // self-loop: 1/deg_tot
        int cm = cnt < 64 ? cnt : 64;
        int2 myp = (lane < cm) ? csr[rs + lane] : make_int2(0, 0);
        int j = 0;
        for (; j + 4 <= cm; j += 4) {
            int s0 = __shfl(myp.x, j),   s1 = __shfl(myp.x, j+1);
            int s2 = __shfl(myp.x, j+2), s3 = __shfl(myp.x, j+3);
            float f0 = __int_as_float(__shfl(myp.y, j));
            float f1 = __int_as_float(__shfl(myp.y, j+1));
            float f2 = __int_as_float(__shfl(myp.y, j+2));
            float f3 = __int_as_float(__shfl(myp.y, j+3));
            float v0 = x[(size_t)s0 * CIN + lane];
            float v1 = x[(size_t)s1 * CIN + lane];
            float v2 = x[(size_t)s2 * CIN + lane];
            float v3 = x[(size_t)s3 * CIN + lane];
            acc = fmaf(f0, v0, acc); acc = fmaf(f1, v1, acc);
            acc = fmaf(f2, v2, acc); acc = fmaf(f3, v3, acc);
        }
        for (; j < cm; ++j) {
            int s = __shfl(myp.x, j);
            float f = __int_as_float(__shfl(myp.y, j));
            acc = fmaf(f, x[(size_t)s * CIN + lane], acc);
        }
        for (int jj = 64; jj < cnt; ++jj) {  // degree >64: essentially never
            int2 p = csr[rs + jj];
            acc = fmaf(__int_as_float(p.y), x[(size_t)p.x * CIN + lane], acc);
        }
        sagg[m][lane] = acc;
    }
    __syncthreads();

    // GEMM: 32x64 agg @ 64x128 W1 ; 4 nodes x 4 outs per thread
    int ot = tid & 31, mt = tid >> 5;
    int o0 = ot * 4, m0 = mt * 4;
    float accr[4][4] = {};
    #pragma unroll 8
    for (int cc = 0; cc < CIN; ++cc) {
        float4 w4 = *(const float4*)&sW[cc * H2X + o0];
        float a0 = sagg[m0 + 0][cc];
        float a1 = sagg[m0 + 1][cc];
        float a2 = sagg[m0 + 2][cc];
        float a3 = sagg[m0 + 3][cc];
        accr[0][0] = fmaf(a0, w4.x, accr[0][0]); accr[0][1] = fmaf(a0, w4.y, accr[0][1]);
        accr[0][2] = fmaf(a0, w4.z, accr[0][2]); accr[0][3] = fmaf(a0, w4.w, accr[0][3]);
        accr[1][0] = fmaf(a1, w4.x, accr[1][0]); accr[1][1] = fmaf(a1, w4.y, accr[1][1]);
        accr[1][2] = fmaf(a1, w4.z, accr[1][2]); accr[1][3] = fmaf(a1, w4.w, accr[1][3]);
        accr[2][0] = fmaf(a2, w4.x, accr[2][0]); accr[2][1] = fmaf(a2, w4.y, accr[2][1]);
        accr[2][2] = fmaf(a2, w4.z, accr[2][2]); accr[2][3] = fmaf(a2, w4.w, accr[2][3]);
        accr[3][0] = fmaf(a3, w4.x, accr[3][0]); accr[3][1] = fmaf(a3, w4.y, accr[3][1]);
        accr[3][2] = fmaf(a3, w4.z, accr[3][2]); accr[3][3] = fmaf(a3, w4.w, accr[3][3]);
    }
    #pragma unroll
    for (int i2 = 0; i2 < 4; ++i2) {
        float4 o;
        o.x = fmaxf(accr[i2][0] + sb[o0 + 0], 0.f);
        o.y = fmaxf(accr[i2][1] + sb[o0 + 1], 0.f);
        o.z = fmaxf(accr[i2][2] + sb[o0 + 2], 0.f);
        o.w = fmaxf(accr[i2][3] + sb[o0 + 3], 0.f);
        *(float4*)&h1[(size_t)(n0 + m0 + i2) * H2X + o0] = o;
    }
}

// ---------------- layer 2 GEMM: t2 = h1 @ W2 ----------------

__global__ __launch_bounds__(256) void k_gemm2(
        const float* __restrict__ h1, const float* __restrict__ W2,
        float* __restrict__ t2) {
    __shared__ float sW[H2X * HID];        // 32 KB
    __shared__ float sh[32][H2X + 4];      // 16.9 KB
    int tid = threadIdx.x;

    const float4* W4 = (const float4*)W2;
    float4* sW4 = (float4*)sW;
    #pragma unroll
    for (int k = 0; k < 8; ++k) sW4[tid + 256*k] = W4[tid + 256*k];

    int n0 = blockIdx.x * 32;
    #pragma unroll
    for (int k = 0; k < 4; ++k) {
        int idx = tid + 256 * k;          // 0..1023 float4s
        int r = idx >> 5;
        int c4 = idx & 31;
        float4 v = *(const float4*)&h1[(size_t)(n0 + r) * H2X + c4 * 4];
        *(float4*)&sh[r][c4 * 4] = v;
    }
    __syncthreads();

    int ot = tid & 15, mt = tid >> 4;      // 16 out-tiles x 16 node-tiles
    int o0 = ot * 4, m0 = mt * 2;
    float accr[2][4] = {};
    #pragma unroll 8
    for (int cc = 0; cc < H2X; ++cc) {
        float4 w4 = *(const float4*)&sW[cc * HID + o0];
        float a0 = sh[m0][cc];
        float a1 = sh[m0 + 1][cc];
        accr[0][0] = fmaf(a0, w4.x, accr[0][0]); accr[0][1] = fmaf(a0, w4.y, accr[0][1]);
        accr[0][2] = fmaf(a0, w4.z, accr[0][2]); accr[0][3] = fmaf(a0, w4.w, accr[0][3]);
        accr[1][0] = fmaf(a1, w4.x, accr[1][0]); accr[1][1] = fmaf(a1, w4.y, accr[1][1]);
        accr[1][2] = fmaf(a1, w4.z, accr[1][2]); accr[1][3] = fmaf(a1, w4.w, accr[1][3]);
    }
    #pragma unroll
    for (int i2 = 0; i2 < 2; ++i2) {
        float4 o;
        o.x = accr[i2][0]; o.y = accr[i2][1]; o.z = accr[i2][2]; o.w = accr[i2][3];
        *(float4*)&t2[(size_t)(n0 + m0 + i2) * HID + o0] = o;
    }
}

// ---------------- layer 2 aggregation: h2 = relu(A_hat t2 + b2) ----------------

__global__ __launch_bounds__(256) void k_agg2(
        const float* __restrict__ t2, const int2* __restrict__ csr,
        const int* __restrict__ rowptr, const int* __restrict__ counts,
        const float* __restrict__ dis, const float* __restrict__ b2,
        float* __restrict__ h2) {
    int tid = threadIdx.x;
    int wave = tid >> 6, lane = tid & 63;
    int n0 = blockIdx.x * 32;
    float bb = b2[lane];
    for (int i = 0; i < 8; ++i) {
        int n = n0 + wave * 8 + i;
        float dn = dis[n];
        int rs = rowptr[n], cnt = counts[n];
        float acc = t2[(size_t)n * HID + lane] * (dn * dn);
        int cm = cnt < 64 ? cnt : 64;
        int2 myp = (lane < cm) ? csr[rs + lane] : make_int2(0, 0);
        int j = 0;
        for (; j + 4 <= cm; j += 4) {
            int s0 = __shfl(myp.x, j),   s1 = __shfl(myp.x, j+1);
            int s2 = __shfl(myp.x, j+2), s3 = __shfl(myp.x, j+3);
            float f0 = __int_as_float(__shfl(myp.y, j));
            float f1 = __int_as_float(__shfl(myp.y, j+1));
            float f2 = __int_as_float(__shfl(myp.y, j+2));
            float f3 = __int_as_float(__shfl(myp.y, j+3));
            float v0 = t2[(size_t)s0 * HID + lane];
            float v1 = t2[(size_t)s1 * HID + lane];
            float v2 = t2[(size_t)s2 * HID + lane];
            float v3 = t2[(size_t)s3 * HID + lane];
            acc = fmaf(f0, v0, acc); acc = fmaf(f1, v1, acc);
            acc = fmaf(f2, v2, acc); acc = fmaf(f3, v3, acc);
        }
        for (; j < cm; ++j) {
            int s = __shfl(myp.x, j);
            float f = __int_as_float(__shfl(myp.y, j));
            acc = fmaf(f, t2[(size_t)s * HID + lane], acc);
        }
        for (int jj = 64; jj < cnt; ++jj) {
            int2 p = csr[rs + jj];
            acc = fmaf(__int_as_float(p.y), t2[(size_t)p.x * HID + lane], acc);
        }
        h2[(size_t)n * HID + lane] = fmaxf(acc + bb, 0.f);
    }
}

// ---------------- FC + softmax ----------------

__global__ __launch_bounds__(256) void k_fc(
        const float* __restrict__ h2, const float* __restrict__ Wfc,
        const float* __restrict__ bfc, float* __restrict__ out) {
    __shared__ float4 red[256];
    int b = blockIdx.x, t = threadIdx.x;
    const float* hrow = h2 + (size_t)b * (HID * NODESG);
    const float4* W4 = (const float4*)Wfc;
    float4 a = make_float4(0.f, 0.f, 0.f, 0.f);
    #pragma unroll 4
    for (int j = 0; j < 32; ++j) {
        int i = j * 256 + t;
        float hv = hrow[i];
        float4 w = W4[i];
        a.x = fmaf(hv, w.x, a.x);
        a.y = fmaf(hv, w.y, a.y);
        a.z = fmaf(hv, w.z, a.z);
        a.w = fmaf(hv, w.w, a.w);
    }
    red[t] = a;
    __syncthreads();
    for (int s = 128; s > 0; s >>= 1) {
        if (t < s) {
            red[t].x += red[t + s].x; red[t].y += red[t + s].y;
            red[t].z += red[t + s].z; red[t].w += red[t + s].w;
        }
        __syncthreads();
    }
    if (t == 0) {
        float l0 = red[0].x + bfc[0];
        float l1 = red[0].y + bfc[1];
        float l2 = red[0].z + bfc[2];
        float l3 = red[0].w + bfc[3];
        float mx = fmaxf(fmaxf(l0, l1), fmaxf(l2, l3));
        float e0 = expf(l0 - mx), e1 = expf(l1 - mx);
        float e2 = expf(l2 - mx), e3 = expf(l3 - mx);
        float inv = 1.f / (e0 + e1 + e2 + e3);
        float4 o = make_float4(e0 * inv, e1 * inv, e2 * inv, e3 * inv);
        *(float4*)&out[(size_t)b * 4] = o;
    }
}

// ---------------- launch ----------------

extern "C" void kernel_launch(void* const* d_in, const int* in_sizes, int n_in,
                              void* d_out, int out_size, void* d_ws, size_t ws_size,
                              hipStream_t stream) {
    const float* x   = (const float*)d_in[0];
    const int*   ei  = (const int*)  d_in[1];
    const float* ea  = (const float*)d_in[2];
    const float* W1  = (const float*)d_in[3];
    const float* b1  = (const float*)d_in[4];
    const float* W2  = (const float*)d_in[5];
    const float* b2  = (const float*)d_in[6];
    const float* Wfc = (const float*)d_in[7];
    const float* bfc = (const float*)d_in[8];
    float* out = (float*)d_out;
    const int* src = ei;
    const int* dst = ei + NE;

    char* ws = (char*)d_ws;
    size_t off = 0;
    float* deg    = (float*)(ws + off); off += (size_t)N_NODES * 4;
    int*   counts = (int*)  (ws + off); off += (size_t)N_NODES * 4;
    int*   cursor = (int*)  (ws + off); off += (size_t)N_NODES * 4;
    int*   rowptr = (int*)  (ws + off); off += (size_t)N_NODES * 4;
    int*   partial= (int*)  (ws + off); off += 1024;
    float* dis    = (float*)(ws + off); off += (size_t)N_NODES * 4;
    int2*  csr    = (int2*) (ws + off); off += (size_t)NE * 8;
    float* h1     = (float*)(ws + off); off += (size_t)N_NODES * H2X * 4;
    float* t2     = (float*)(ws + off); off += (size_t)N_NODES * HID * 4;
    float* h2     = h1;  // h1 dead after k_gemm2; reuse

    // zero deg + counts + cursor (contiguous)
    hipMemsetAsync(ws, 0, (size_t)N_NODES * 12, stream);

    k_edge_deg<<<NE / 256, 256, 0, stream>>>(dst, ea, deg, counts);
    k_dis<<<N_NODES / 256, 256, 0, stream>>>(deg, dis);
    k_scan1<<<256, 256, 0, stream>>>(counts, rowptr, partial);
    k_scan2<<<1, 256, 0, stream>>>(partial);
    k_scan3<<<N_NODES / 256, 256, 0, stream>>>(rowptr, partial);
    k_edge_csr<<<NE / 256, 256, 0, stream>>>(src, dst, ea, dis, rowptr, cursor, csr);
    k_layer1<<<N_NODES / 32, 256, 0, stream>>>(x, csr, rowptr, counts, dis, W1, b1, h1);
    k_gemm2<<<N_NODES / 32, 256, 0, stream>>>(h1, W2, t2);
    k_agg2<<<N_NODES / 32, 256, 0, stream>>>(t2, csr, rowptr, counts, dis, b2, h2);
    k_fc<<<NGRAPH, 256, 0, stream>>>(h2, Wfc, bfc, out);
}

// Round 2
// 548.990 us; speedup vs baseline: 1.2101x; 1.2101x over previous
//
#include <hip/hip_runtime.h>

#define N_NODES 131072
#define NE      2097152
#define CIN     64
#define HID     64
#define H2X     128   // 2*HID
#define NODESG  128   // nodes per graph
#define NGRAPH  1024
#define NCLS    4

#define FIXSCALE 16777216.0f          // 2^24
#define FIXMASK  ((1ull << 40) - 1)

// ---------------- pass 1: fused histogram (count + weighted degree) + rank ----
// one u64 atomic per edge; old value's count field = this edge's CSR slot.

__global__ void k_pass1(const int* __restrict__ dst, const float* __restrict__ ew,
                        unsigned long long* __restrict__ packed,
                        int* __restrict__ pos) {
    int e = blockIdx.x * blockDim.x + threadIdx.x;
    if (e < NE) {
        int d = dst[e];
        unsigned long long add = (1ull << 40) |
            (unsigned long long)(ew[e] * FIXSCALE);
        unsigned long long old = atomicAdd(&packed[d], add);
        pos[e] = (int)(old >> 40);
    }
}

// unpack: dis = rsqrt(deg+1), counts = edge count
__global__ void k_dis(const unsigned long long* __restrict__ packed,
                      float* __restrict__ dis, int* __restrict__ counts) {
    int n = blockIdx.x * blockDim.x + threadIdx.x;
    if (n < N_NODES) {
        unsigned long long p = packed[n];
        float deg = (float)(p & FIXMASK) * (1.0f / FIXSCALE);
        dis[n] = rsqrtf(deg + 1.0f);            // +1 = self-loop weight
        counts[n] = (int)(p >> 40);
    }
}

// exclusive scan of counts -> rowptr, chunk = 512/block
__global__ void k_scan1(const int* __restrict__ counts, int* __restrict__ rowptr,
                        int* __restrict__ partial) {
    __shared__ int sd[256];
    int t = threadIdx.x;
    int base = blockIdx.x * 512;
    int c0 = counts[base + 2*t];
    int c1 = counts[base + 2*t + 1];
    int loc = c0 + c1;
    sd[t] = loc;
    __syncthreads();
    for (int off = 1; off < 256; off <<= 1) {
        int v = (t >= off) ? sd[t - off] : 0;
        __syncthreads();
        sd[t] += v;
        __syncthreads();
    }
    int excl = sd[t] - loc;
    rowptr[base + 2*t]     = excl;
    rowptr[base + 2*t + 1] = excl + c0;
    if (t == 255) partial[blockIdx.x] = sd[t];
}

__global__ void k_scan2(int* __restrict__ partial) {
    __shared__ int sd[256];
    int t = threadIdx.x;
    int v0 = partial[t];
    sd[t] = v0;
    __syncthreads();
    for (int off = 1; off < 256; off <<= 1) {
        int v = (t >= off) ? sd[t - off] : 0;
        __syncthreads();
        sd[t] += v;
        __syncthreads();
    }
    partial[t] = sd[t] - v0;  // exclusive
}

__global__ void k_scan3(int* __restrict__ rowptr, const int* __restrict__ partial) {
    int i = blockIdx.x * blockDim.x + threadIdx.x;
    if (i < N_NODES) rowptr[i] += partial[i >> 9];
}

// CSR fill — NO atomics: slot comes from pass1's rank.
__global__ void k_edge_csr(const int* __restrict__ src, const int* __restrict__ dst,
                           const float* __restrict__ ew, const float* __restrict__ dis,
                           const int* __restrict__ rowptr, const int* __restrict__ pos,
                           int2* __restrict__ csr) {
    int e = blockIdx.x * blockDim.x + threadIdx.x;
    if (e < NE) {
        int s = src[e], d = dst[e];
        float nrm = dis[s] * ew[e] * dis[d];
        csr[rowptr[d] + pos[e]] = make_int2(s, __float_as_int(nrm));
    }
}

// ---------------- layer 1: h1 = relu( (A_hat x) @ W1 + b1 ) ----------------
// block = 256 thr (4 waves), 32 nodes/block (8 per wave, lane = channel)

__global__ __launch_bounds__(256) void k_layer1(
        const float* __restrict__ x, const int2* __restrict__ csr,
        const int* __restrict__ rowptr, const int* __restrict__ counts,
        const float* __restrict__ dis, const float* __restrict__ W1,
        const float* __restrict__ b1, float* __restrict__ h1) {
    __shared__ float sW[CIN * H2X];           // 32 KB
    __shared__ float sb[H2X];
    __shared__ float sagg[32][CIN + 1];       // pad for bank spread
    int tid = threadIdx.x;

    const float4* W4 = (const float4*)W1;
    float4* sW4 = (float4*)sW;
    #pragma unroll
    for (int k = 0; k < 8; ++k) sW4[tid + 256*k] = W4[tid + 256*k];
    if (tid < H2X) sb[tid] = b1[tid];

    int wave = tid >> 6, lane = tid & 63;
    int n0 = blockIdx.x * 32;

    for (int i = 0; i < 8; ++i) {
        int m = wave * 8 + i;
        int n = n0 + m;
        float dn = dis[n];
        int rs = rowptr[n], cnt = counts[n];
        float acc = x[(size_t)n * CIN + lane] * (dn * dn);   // self-loop: 1/deg_tot
        int cm = cnt < 64 ? cnt : 64;
        int2 myp = (lane < cm) ? csr[rs + lane] : make_int2(0, 0);
        int j = 0;
        for (; j + 4 <= cm; j += 4) {
            int s0 = __shfl(myp.x, j),   s1 = __shfl(myp.x, j+1);
            int s2 = __shfl(myp.x, j+2), s3 = __shfl(myp.x, j+3);
            float f0 = __int_as_float(__shfl(myp.y, j));
            float f1 = __int_as_float(__shfl(myp.y, j+1));
            float f2 = __int_as_float(__shfl(myp.y, j+2));
            float f3 = __int_as_float(__shfl(myp.y, j+3));
            float v0 = x[(size_t)s0 * CIN + lane];
            float v1 = x[(size_t)s1 * CIN + lane];
            float v2 = x[(size_t)s2 * CIN + lane];
            float v3 = x[(size_t)s3 * CIN + lane];
            acc = fmaf(f0, v0, acc); acc = fmaf(f1, v1, acc);
            acc = fmaf(f2, v2, acc); acc = fmaf(f3, v3, acc);
        }
        for (; j < cm; ++j) {
            int s = __shfl(myp.x, j);
            float f = __int_as_float(__shfl(myp.y, j));
            acc = fmaf(f, x[(size_t)s * CIN + lane], acc);
        }
        for (int jj = 64; jj < cnt; ++jj) {  // degree >64: essentially never
            int2 p = csr[rs + jj];
            acc = fmaf(__int_as_float(p.y), x[(size_t)p.x * CIN + lane], acc);
        }
        sagg[m][lane] = acc;
    }
    __syncthreads();

    // GEMM: 32x64 agg @ 64x128 W1 ; 4 nodes x 4 outs per thread
    int ot = tid & 31, mt = tid >> 5;
    int o0 = ot * 4, m0 = mt * 4;
    float accr[4][4] = {};
    #pragma unroll 8
    for (int cc = 0; cc < CIN; ++cc) {
        float4 w4 = *(const float4*)&sW[cc * H2X + o0];
        float a0 = sagg[m0 + 0][cc];
        float a1 = sagg[m0 + 1][cc];
        float a2 = sagg[m0 + 2][cc];
        float a3 = sagg[m0 + 3][cc];
        accr[0][0] = fmaf(a0, w4.x, accr[0][0]); accr[0][1] = fmaf(a0, w4.y, accr[0][1]);
        accr[0][2] = fmaf(a0, w4.z, accr[0][2]); accr[0][3] = fmaf(a0, w4.w, accr[0][3]);
        accr[1][0] = fmaf(a1, w4.x, accr[1][0]); accr[1][1] = fmaf(a1, w4.y, accr[1][1]);
        accr[1][2] = fmaf(a1, w4.z, accr[1][2]); accr[1][3] = fmaf(a1, w4.w, accr[1][3]);
        accr[2][0] = fmaf(a2, w4.x, accr[2][0]); accr[2][1] = fmaf(a2, w4.y, accr[2][1]);
        accr[2][2] = fmaf(a2, w4.z, accr[2][2]); accr[2][3] = fmaf(a2, w4.w, accr[2][3]);
        accr[3][0] = fmaf(a3, w4.x, accr[3][0]); accr[3][1] = fmaf(a3, w4.y, accr[3][1]);
        accr[3][2] = fmaf(a3, w4.z, accr[3][2]); accr[3][3] = fmaf(a3, w4.w, accr[3][3]);
    }
    #pragma unroll
    for (int i2 = 0; i2 < 4; ++i2) {
        float4 o;
        o.x = fmaxf(accr[i2][0] + sb[o0 + 0], 0.f);
        o.y = fmaxf(accr[i2][1] + sb[o0 + 1], 0.f);
        o.z = fmaxf(accr[i2][2] + sb[o0 + 2], 0.f);
        o.w = fmaxf(accr[i2][3] + sb[o0 + 3], 0.f);
        *(float4*)&h1[(size_t)(n0 + m0 + i2) * H2X + o0] = o;
    }
}

// ---------------- layer 2 GEMM: t2 = h1 @ W2 ----------------

__global__ __launch_bounds__(256) void k_gemm2(
        const float* __restrict__ h1, const float* __restrict__ W2,
        float* __restrict__ t2) {
    __shared__ float sW[H2X * HID];        // 32 KB
    __shared__ float sh[32][H2X + 4];      // 16.9 KB
    int tid = threadIdx.x;

    const float4* W4 = (const float4*)W2;
    float4* sW4 = (float4*)sW;
    #pragma unroll
    for (int k = 0; k < 8; ++k) sW4[tid + 256*k] = W4[tid + 256*k];

    int n0 = blockIdx.x * 32;
    #pragma unroll
    for (int k = 0; k < 4; ++k) {
        int idx = tid + 256 * k;          // 0..1023 float4s
        int r = idx >> 5;
        int c4 = idx & 31;
        float4 v = *(const float4*)&h1[(size_t)(n0 + r) * H2X + c4 * 4];
        *(float4*)&sh[r][c4 * 4] = v;
    }
    __syncthreads();

    int ot = tid & 15, mt = tid >> 4;      // 16 out-tiles x 16 node-tiles
    int o0 = ot * 4, m0 = mt * 2;
    float accr[2][4] = {};
    #pragma unroll 8
    for (int cc = 0; cc < H2X; ++cc) {
        float4 w4 = *(const float4*)&sW[cc * HID + o0];
        float a0 = sh[m0][cc];
        float a1 = sh[m0 + 1][cc];
        accr[0][0] = fmaf(a0, w4.x, accr[0][0]); accr[0][1] = fmaf(a0, w4.y, accr[0][1]);
        accr[0][2] = fmaf(a0, w4.z, accr[0][2]); accr[0][3] = fmaf(a0, w4.w, accr[0][3]);
        accr[1][0] = fmaf(a1, w4.x, accr[1][0]); accr[1][1] = fmaf(a1, w4.y, accr[1][1]);
        accr[1][2] = fmaf(a1, w4.z, accr[1][2]); accr[1][3] = fmaf(a1, w4.w, accr[1][3]);
    }
    #pragma unroll
    for (int i2 = 0; i2 < 2; ++i2) {
        float4 o;
        o.x = accr[i2][0]; o.y = accr[i2][1]; o.z = accr[i2][2]; o.w = accr[i2][3];
        *(float4*)&t2[(size_t)(n0 + m0 + i2) * HID + o0] = o;
    }
}

// ---------------- layer 2 aggregation: h2 = relu(A_hat t2 + b2) ----------------

__global__ __launch_bounds__(256) void k_agg2(
        const float* __restrict__ t2, const int2* __restrict__ csr,
        const int* __restrict__ rowptr, const int* __restrict__ counts,
        const float* __restrict__ dis, const float* __restrict__ b2,
        float* __restrict__ h2) {
    int tid = threadIdx.x;
    int wave = tid >> 6, lane = tid & 63;
    int n0 = blockIdx.x * 32;
    float bb = b2[lane];
    for (int i = 0; i < 8; ++i) {
        int n = n0 + wave * 8 + i;
        float dn = dis[n];
        int rs = rowptr[n], cnt = counts[n];
        float acc = t2[(size_t)n * HID + lane] * (dn * dn);
        int cm = cnt < 64 ? cnt : 64;
        int2 myp = (lane < cm) ? csr[rs + lane] : make_int2(0, 0);
        int j = 0;
        for (; j + 4 <= cm; j += 4) {
            int s0 = __shfl(myp.x, j),   s1 = __shfl(myp.x, j+1);
            int s2 = __shfl(myp.x, j+2), s3 = __shfl(myp.x, j+3);
            float f0 = __int_as_float(__shfl(myp.y, j));
            float f1 = __int_as_float(__shfl(myp.y, j+1));
            float f2 = __int_as_float(__shfl(myp.y, j+2));
            float f3 = __int_as_float(__shfl(myp.y, j+3));
            float v0 = t2[(size_t)s0 * HID + lane];
            float v1 = t2[(size_t)s1 * HID + lane];
            float v2 = t2[(size_t)s2 * HID + lane];
            float v3 = t2[(size_t)s3 * HID + lane];
            acc = fmaf(f0, v0, acc); acc = fmaf(f1, v1, acc);
            acc = fmaf(f2, v2, acc); acc = fmaf(f3, v3, acc);
        }
        for (; j < cm; ++j) {
            int s = __shfl(myp.x, j);
            float f = __int_as_float(__shfl(myp.y, j));
            acc = fmaf(f, t2[(size_t)s * HID + lane], acc);
        }
        for (int jj = 64; jj < cnt; ++jj) {
            int2 p = csr[rs + jj];
            acc = fmaf(__int_as_float(p.y), t2[(size_t)p.x * HID + lane], acc);
        }
        h2[(size_t)n * HID + lane] = fmaxf(acc + bb, 0.f);
    }
}

// ---------------- FC + softmax ----------------

__global__ __launch_bounds__(256) void k_fc(
        const float* __restrict__ h2, const float* __restrict__ Wfc,
        const float* __restrict__ bfc, float* __restrict__ out) {
    __shared__ float4 red[256];
    int b = blockIdx.x, t = threadIdx.x;
    const float* hrow = h2 + (size_t)b * (HID * NODESG);
    const float4* W4 = (const float4*)Wfc;
    float4 a = make_float4(0.f, 0.f, 0.f, 0.f);
    #pragma unroll 4
    for (int j = 0; j < 32; ++j) {
        int i = j * 256 + t;
        float hv = hrow[i];
        float4 w = W4[i];
        a.x = fmaf(hv, w.x, a.x);
        a.y = fmaf(hv, w.y, a.y);
        a.z = fmaf(hv, w.z, a.z);
        a.w = fmaf(hv, w.w, a.w);
    }
    red[t] = a;
    __syncthreads();
    for (int s = 128; s > 0; s >>= 1) {
        if (t < s) {
            red[t].x += red[t + s].x; red[t].y += red[t + s].y;
            red[t].z += red[t + s].z; red[t].w += red[t + s].w;
        }
        __syncthreads();
    }
    if (t == 0) {
        float l0 = red[0].x + bfc[0];
        float l1 = red[0].y + bfc[1];
        float l2 = red[0].z + bfc[2];
        float l3 = red[0].w + bfc[3];
        float mx = fmaxf(fmaxf(l0, l1), fmaxf(l2, l3));
        float e0 = expf(l0 - mx), e1 = expf(l1 - mx);
        float e2 = expf(l2 - mx), e3 = expf(l3 - mx);
        float inv = 1.f / (e0 + e1 + e2 + e3);
        float4 o = make_float4(e0 * inv, e1 * inv, e2 * inv, e3 * inv);
        *(float4*)&out[(size_t)b * 4] = o;
    }
}

// ---------------- launch ----------------

extern "C" void kernel_launch(void* const* d_in, const int* in_sizes, int n_in,
                              void* d_out, int out_size, void* d_ws, size_t ws_size,
                              hipStream_t stream) {
    const float* x   = (const float*)d_in[0];
    const int*   ei  = (const int*)  d_in[1];
    const float* ea  = (const float*)d_in[2];
    const float* W1  = (const float*)d_in[3];
    const float* b1  = (const float*)d_in[4];
    const float* W2  = (const float*)d_in[5];
    const float* b2  = (const float*)d_in[6];
    const float* Wfc = (const float*)d_in[7];
    const float* bfc = (const float*)d_in[8];
    float* out = (float*)d_out;
    const int* src = ei;
    const int* dst = ei + NE;

    char* ws = (char*)d_ws;
    size_t off = 0;
    unsigned long long* packed = (unsigned long long*)(ws + off); off += (size_t)N_NODES * 8;
    int*   counts = (int*)  (ws + off); off += (size_t)N_NODES * 4;
    int*   rowptr = (int*)  (ws + off); off += (size_t)N_NODES * 4;
    int*   partial= (int*)  (ws + off); off += 1024;
    float* dis    = (float*)(ws + off); off += (size_t)N_NODES * 4;
    int2*  csr    = (int2*) (ws + off); off += (size_t)NE * 8;
    float* h1     = (float*)(ws + off); off += (size_t)N_NODES * H2X * 4;
    float* t2     = (float*)(ws + off); off += (size_t)N_NODES * HID * 4;
    float* h2     = h1;                 // h1 dead after k_gemm2; reuse
    int*   pos    = (int*)h1;           // pos dead before h1 is written; alias

    // zero the packed histogram only
    hipMemsetAsync(packed, 0, (size_t)N_NODES * 8, stream);

    k_pass1<<<NE / 256, 256, 0, stream>>>(dst, ea, packed, pos);
    k_dis<<<N_NODES / 256, 256, 0, stream>>>(packed, dis, counts);
    k_scan1<<<256, 256, 0, stream>>>(counts, rowptr, partial);
    k_scan2<<<1, 256, 0, stream>>>(partial);
    k_scan3<<<N_NODES / 256, 256, 0, stream>>>(rowptr, partial);
    k_edge_csr<<<NE / 256, 256, 0, stream>>>(src, dst, ea, dis, rowptr, pos, csr);
    k_layer1<<<N_NODES / 32, 256, 0, stream>>>(x, csr, rowptr, counts, dis, W1, b1, h1);
    k_gemm2<<<N_NODES / 32, 256, 0, stream>>>(h1, W2, t2);
    k_agg2<<<N_NODES / 32, 256, 0, stream>>>(t2, csr, rowptr, counts, dis, b2, h2);
    k_fc<<<NGRAPH, 256, 0, stream>>>(h2, Wfc, bfc, out);
}

// Round 3
// 463.972 us; speedup vs baseline: 1.4319x; 1.1832x over previous
//
#include <hip/hip_runtime.h>

#define N_NODES 131072
#define NE      2097152
#define CIN     64
#define HID     64
#define H2X     128   // 2*HID
#define NODESG  128   // nodes per graph
#define NGRAPH  1024
#define NCLS    4

#define FIXSCALE 16777216.0f          // 2^24
#define FIXMASK  ((1ull << 40) - 1)

// bf16 helpers (RNE; inputs finite)
__device__ __forceinline__ unsigned short f2b(float f) {
    unsigned int u = __float_as_uint(f);
    return (unsigned short)((u + 0x7fffu + ((u >> 16) & 1u)) >> 16);
}
__device__ __forceinline__ float b2f(unsigned short b) {
    return __uint_as_float((unsigned int)b << 16);
}
__device__ __forceinline__ unsigned int pack2(float a, float b) {
    return (unsigned int)f2b(a) | ((unsigned int)f2b(b) << 16);
}

// ---------------- pass 1: fused histogram (count + weighted degree) + rank ----

__global__ void k_pass1(const int* __restrict__ dst, const float* __restrict__ ew,
                        unsigned long long* __restrict__ packed,
                        int* __restrict__ pos) {
    int e = blockIdx.x * blockDim.x + threadIdx.x;
    if (e < NE) {
        int d = dst[e];
        unsigned long long add = (1ull << 40) |
            (unsigned long long)(ew[e] * FIXSCALE);
        unsigned long long old = atomicAdd(&packed[d], add);
        pos[e] = (int)(old >> 40);
    }
}

// x -> bf16 table (4 floats / thread)
__global__ void k_xcast(const float* __restrict__ x, unsigned short* __restrict__ xb) {
    int i = blockIdx.x * blockDim.x + threadIdx.x;
    float4 v = ((const float4*)x)[i];
    ((uint2*)xb)[i] = make_uint2(pack2(v.x, v.y), pack2(v.z, v.w));
}

// unpack: dis = rsqrt(deg+1), counts = edge count
__global__ void k_dis(const unsigned long long* __restrict__ packed,
                      float* __restrict__ dis, int* __restrict__ counts) {
    int n = blockIdx.x * blockDim.x + threadIdx.x;
    if (n < N_NODES) {
        unsigned long long p = packed[n];
        float deg = (float)(p & FIXMASK) * (1.0f / FIXSCALE);
        dis[n] = rsqrtf(deg + 1.0f);            // +1 = self-loop weight
        counts[n] = (int)(p >> 40);
    }
}

// exclusive scan of counts -> rowptr, chunk = 512/block
__global__ void k_scan1(const int* __restrict__ counts, int* __restrict__ rowptr,
                        int* __restrict__ partial) {
    __shared__ int sd[256];
    int t = threadIdx.x;
    int base = blockIdx.x * 512;
    int c0 = counts[base + 2*t];
    int c1 = counts[base + 2*t + 1];
    int loc = c0 + c1;
    sd[t] = loc;
    __syncthreads();
    for (int off = 1; off < 256; off <<= 1) {
        int v = (t >= off) ? sd[t - off] : 0;
        __syncthreads();
        sd[t] += v;
        __syncthreads();
    }
    int excl = sd[t] - loc;
    rowptr[base + 2*t]     = excl;
    rowptr[base + 2*t + 1] = excl + c0;
    if (t == 255) partial[blockIdx.x] = sd[t];
}

__global__ void k_scan2(int* __restrict__ partial) {
    __shared__ int sd[256];
    int t = threadIdx.x;
    int v0 = partial[t];
    sd[t] = v0;
    __syncthreads();
    for (int off = 1; off < 256; off <<= 1) {
        int v = (t >= off) ? sd[t - off] : 0;
        __syncthreads();
        sd[t] += v;
        __syncthreads();
    }
    partial[t] = sd[t] - v0;  // exclusive
}

__global__ void k_scan3(int* __restrict__ rowptr, const int* __restrict__ partial) {
    int i = blockIdx.x * blockDim.x + threadIdx.x;
    if (i < N_NODES) rowptr[i] += partial[i >> 9];
}

// CSR fill — no atomics: slot comes from pass1's rank.
__global__ void k_edge_csr(const int* __restrict__ src, const int* __restrict__ dst,
                           const float* __restrict__ ew, const float* __restrict__ dis,
                           const int* __restrict__ rowptr, const int* __restrict__ pos,
                           int2* __restrict__ csr) {
    int e = blockIdx.x * blockDim.x + threadIdx.x;
    if (e < NE) {
        int s = src[e], d = dst[e];
        float nrm = dis[s] * ew[e] * dis[d];
        csr[rowptr[d] + pos[e]] = make_int2(s, __float_as_int(nrm));
    }
}

// ---------------- layer 1: h1 = relu( (A_hat xb) @ W1 + b1 ) ----------------
// bf16 gather table; W1 in LDS as bf16 (16KB) -> 6 blocks/CU.

__global__ __launch_bounds__(256, 6) void k_layer1(
        const unsigned short* __restrict__ xb, const int2* __restrict__ csr,
        const int* __restrict__ rowptr, const int* __restrict__ counts,
        const float* __restrict__ dis, const float* __restrict__ W1,
        const float* __restrict__ b1, float* __restrict__ h1) {
    __shared__ unsigned int sWb[CIN * H2X / 2];   // 16 KB bf16 pairs
    __shared__ float sb[H2X];
    __shared__ float sagg[32][CIN + 1];           // pad for bank spread
    int tid = threadIdx.x;

    const float4* W4 = (const float4*)W1;
    #pragma unroll
    for (int k = 0; k < 8; ++k) {
        float4 v = W4[tid + 256*k];
        ((uint2*)sWb)[tid + 256*k] = make_uint2(pack2(v.x, v.y), pack2(v.z, v.w));
    }
    if (tid < H2X) sb[tid] = b1[tid];

    int wave = tid >> 6, lane = tid & 63;
    int n0 = blockIdx.x * 32;

    for (int i = 0; i < 8; ++i) {
        int m = wave * 8 + i;
        int n = n0 + m;
        float dn = dis[n];
        int rs = rowptr[n], cnt = counts[n];
        float acc = b2f(xb[(size_t)n * CIN + lane]) * (dn * dn);  // self-loop
        int cm = cnt < 64 ? cnt : 64;
        int2 myp = (lane < cm) ? csr[rs + lane] : make_int2(0, 0);
        int j = 0;
        for (; j + 8 <= cm; j += 8) {
            int s[8]; float f[8], v[8];
            #pragma unroll
            for (int q = 0; q < 8; ++q) {
                s[q] = __shfl(myp.x, j + q);
                f[q] = __int_as_float(__shfl(myp.y, j + q));
            }
            #pragma unroll
            for (int q = 0; q < 8; ++q) v[q] = b2f(xb[(size_t)s[q] * CIN + lane]);
            #pragma unroll
            for (int q = 0; q < 8; ++q) acc = fmaf(f[q], v[q], acc);
        }
        for (; j + 4 <= cm; j += 4) {
            int s[4]; float f[4], v[4];
            #pragma unroll
            for (int q = 0; q < 4; ++q) {
                s[q] = __shfl(myp.x, j + q);
                f[q] = __int_as_float(__shfl(myp.y, j + q));
            }
            #pragma unroll
            for (int q = 0; q < 4; ++q) v[q] = b2f(xb[(size_t)s[q] * CIN + lane]);
            #pragma unroll
            for (int q = 0; q < 4; ++q) acc = fmaf(f[q], v[q], acc);
        }
        for (; j < cm; ++j) {
            int s = __shfl(myp.x, j);
            float f = __int_as_float(__shfl(myp.y, j));
            acc = fmaf(f, b2f(xb[(size_t)s * CIN + lane]), acc);
        }
        for (int jj = 64; jj < cnt; ++jj) {   // degree >64: essentially never
            int2 p = csr[rs + jj];
            acc = fmaf(__int_as_float(p.y), b2f(xb[(size_t)p.x * CIN + lane]), acc);
        }
        sagg[m][lane] = acc;
    }
    __syncthreads();

    // GEMM: 32x64 agg @ 64x128 W1 ; 4 nodes x 4 outs per thread
    int ot = tid & 31, mt = tid >> 5;
    int o0 = ot * 4, m0 = mt * 4;
    float accr[4][4] = {};
    #pragma unroll 8
    for (int cc = 0; cc < CIN; ++cc) {
        uint2 wu = ((const uint2*)sWb)[cc * 32 + ot];
        float w0 = __uint_as_float(wu.x << 16);
        float w1 = __uint_as_float(wu.x & 0xffff0000u);
        float w2 = __uint_as_float(wu.y << 16);
        float w3 = __uint_as_float(wu.y & 0xffff0000u);
        float a0 = sagg[m0 + 0][cc];
        float a1 = sagg[m0 + 1][cc];
        float a2 = sagg[m0 + 2][cc];
        float a3 = sagg[m0 + 3][cc];
        accr[0][0] = fmaf(a0, w0, accr[0][0]); accr[0][1] = fmaf(a0, w1, accr[0][1]);
        accr[0][2] = fmaf(a0, w2, accr[0][2]); accr[0][3] = fmaf(a0, w3, accr[0][3]);
        accr[1][0] = fmaf(a1, w0, accr[1][0]); accr[1][1] = fmaf(a1, w1, accr[1][1]);
        accr[1][2] = fmaf(a1, w2, accr[1][2]); accr[1][3] = fmaf(a1, w3, accr[1][3]);
        accr[2][0] = fmaf(a2, w0, accr[2][0]); accr[2][1] = fmaf(a2, w1, accr[2][1]);
        accr[2][2] = fmaf(a2, w2, accr[2][2]); accr[2][3] = fmaf(a2, w3, accr[2][3]);
        accr[3][0] = fmaf(a3, w0, accr[3][0]); accr[3][1] = fmaf(a3, w1, accr[3][1]);
        accr[3][2] = fmaf(a3, w2, accr[3][2]); accr[3][3] = fmaf(a3, w3, accr[3][3]);
    }
    #pragma unroll
    for (int i2 = 0; i2 < 4; ++i2) {
        float4 o;
        o.x = fmaxf(accr[i2][0] + sb[o0 + 0], 0.f);
        o.y = fmaxf(accr[i2][1] + sb[o0 + 1], 0.f);
        o.z = fmaxf(accr[i2][2] + sb[o0 + 2], 0.f);
        o.w = fmaxf(accr[i2][3] + sb[o0 + 3], 0.f);
        *(float4*)&h1[(size_t)(n0 + m0 + i2) * H2X + o0] = o;
    }
}

// ---------------- layer 2 GEMM: t2b = bf16( h1 @ W2 ) ----------------

__global__ __launch_bounds__(256) void k_gemm2(
        const float* __restrict__ h1, const float* __restrict__ W2,
        unsigned short* __restrict__ t2b) {
    __shared__ float sW[H2X * HID];        // 32 KB
    __shared__ float sh[32][H2X + 4];      // 16.9 KB
    int tid = threadIdx.x;

    const float4* W4 = (const float4*)W2;
    float4* sW4 = (float4*)sW;
    #pragma unroll
    for (int k = 0; k < 8; ++k) sW4[tid + 256*k] = W4[tid + 256*k];

    int n0 = blockIdx.x * 32;
    #pragma unroll
    for (int k = 0; k < 4; ++k) {
        int idx = tid + 256 * k;          // 0..1023 float4s
        int r = idx >> 5;
        int c4 = idx & 31;
        float4 v = *(const float4*)&h1[(size_t)(n0 + r) * H2X + c4 * 4];
        *(float4*)&sh[r][c4 * 4] = v;
    }
    __syncthreads();

    int ot = tid & 15, mt = tid >> 4;      // 16 out-tiles x 16 node-tiles
    int o0 = ot * 4, m0 = mt * 2;
    float accr[2][4] = {};
    #pragma unroll 8
    for (int cc = 0; cc < H2X; ++cc) {
        float4 w4 = *(const float4*)&sW[cc * HID + o0];
        float a0 = sh[m0][cc];
        float a1 = sh[m0 + 1][cc];
        accr[0][0] = fmaf(a0, w4.x, accr[0][0]); accr[0][1] = fmaf(a0, w4.y, accr[0][1]);
        accr[0][2] = fmaf(a0, w4.z, accr[0][2]); accr[0][3] = fmaf(a0, w4.w, accr[0][3]);
        accr[1][0] = fmaf(a1, w4.x, accr[1][0]); accr[1][1] = fmaf(a1, w4.y, accr[1][1]);
        accr[1][2] = fmaf(a1, w4.z, accr[1][2]); accr[1][3] = fmaf(a1, w4.w, accr[1][3]);
    }
    #pragma unroll
    for (int i2 = 0; i2 < 2; ++i2) {
        unsigned int a = pack2(accr[i2][0], accr[i2][1]);
        unsigned int b = pack2(accr[i2][2], accr[i2][3]);
        ((uint2*)t2b)[(size_t)(n0 + m0 + i2) * (HID/4) + (o0 >> 2)] = make_uint2(a, b);
    }
}

// ---------------- layer 2 aggregation: h2 = relu(A_hat t2b + b2) ----------------

__global__ __launch_bounds__(256) void k_agg2(
        const unsigned short* __restrict__ t2b, const int2* __restrict__ csr,
        const int* __restrict__ rowptr, const int* __restrict__ counts,
        const float* __restrict__ dis, const float* __restrict__ b2,
        float* __restrict__ h2) {
    int tid = threadIdx.x;
    int wave = tid >> 6, lane = tid & 63;
    int n0 = blockIdx.x * 32;
    float bb = b2[lane];
    for (int i = 0; i < 8; ++i) {
        int n = n0 + wave * 8 + i;
        float dn = dis[n];
        int rs = rowptr[n], cnt = counts[n];
        float acc = b2f(t2b[(size_t)n * HID + lane]) * (dn * dn);
        int cm = cnt < 64 ? cnt : 64;
        int2 myp = (lane < cm) ? csr[rs + lane] : make_int2(0, 0);
        int j = 0;
        for (; j + 8 <= cm; j += 8) {
            int s[8]; float f[8], v[8];
            #pragma unroll
            for (int q = 0; q < 8; ++q) {
                s[q] = __shfl(myp.x, j + q);
                f[q] = __int_as_float(__shfl(myp.y, j + q));
            }
            #pragma unroll
            for (int q = 0; q < 8; ++q) v[q] = b2f(t2b[(size_t)s[q] * HID + lane]);
            #pragma unroll
            for (int q = 0; q < 8; ++q) acc = fmaf(f[q], v[q], acc);
        }
        for (; j + 4 <= cm; j += 4) {
            int s[4]; float f[4], v[4];
            #pragma unroll
            for (int q = 0; q < 4; ++q) {
                s[q] = __shfl(myp.x, j + q);
                f[q] = __int_as_float(__shfl(myp.y, j + q));
            }
            #pragma unroll
            for (int q = 0; q < 4; ++q) v[q] = b2f(t2b[(size_t)s[q] * HID + lane]);
            #pragma unroll
            for (int q = 0; q < 4; ++q) acc = fmaf(f[q], v[q], acc);
        }
        for (; j < cm; ++j) {
            int s = __shfl(myp.x, j);
            float f = __int_as_float(__shfl(myp.y, j));
            acc = fmaf(f, b2f(t2b[(size_t)s * HID + lane]), acc);
        }
        for (int jj = 64; jj < cnt; ++jj) {
            int2 p = csr[rs + jj];
            acc = fmaf(__int_as_float(p.y), b2f(t2b[(size_t)p.x * HID + lane]), acc);
        }
        h2[(size_t)n * HID + lane] = fmaxf(acc + bb, 0.f);
    }
}

// ---------------- FC + softmax ----------------

__global__ __launch_bounds__(256) void k_fc(
        const float* __restrict__ h2, const float* __restrict__ Wfc,
        const float* __restrict__ bfc, float* __restrict__ out) {
    __shared__ float4 red[256];
    int b = blockIdx.x, t = threadIdx.x;
    const float* hrow = h2 + (size_t)b * (HID * NODESG);
    const float4* W4 = (const float4*)Wfc;
    float4 a = make_float4(0.f, 0.f, 0.f, 0.f);
    #pragma unroll 4
    for (int j = 0; j < 32; ++j) {
        int i = j * 256 + t;
        float hv = hrow[i];
        float4 w = W4[i];
        a.x = fmaf(hv, w.x, a.x);
        a.y = fmaf(hv, w.y, a.y);
        a.z = fmaf(hv, w.z, a.z);
        a.w = fmaf(hv, w.w, a.w);
    }
    red[t] = a;
    __syncthreads();
    for (int s = 128; s > 0; s >>= 1) {
        if (t < s) {
            red[t].x += red[t + s].x; red[t].y += red[t + s].y;
            red[t].z += red[t + s].z; red[t].w += red[t + s].w;
        }
        __syncthreads();
    }
    if (t == 0) {
        float l0 = red[0].x + bfc[0];
        float l1 = red[0].y + bfc[1];
        float l2 = red[0].z + bfc[2];
        float l3 = red[0].w + bfc[3];
        float mx = fmaxf(fmaxf(l0, l1), fmaxf(l2, l3));
        float e0 = expf(l0 - mx), e1 = expf(l1 - mx);
        float e2 = expf(l2 - mx), e3 = expf(l3 - mx);
        float inv = 1.f / (e0 + e1 + e2 + e3);
        float4 o = make_float4(e0 * inv, e1 * inv, e2 * inv, e3 * inv);
        *(float4*)&out[(size_t)b * 4] = o;
    }
}

// ---------------- launch ----------------

extern "C" void kernel_launch(void* const* d_in, const int* in_sizes, int n_in,
                              void* d_out, int out_size, void* d_ws, size_t ws_size,
                              hipStream_t stream) {
    const float* x   = (const float*)d_in[0];
    const int*   ei  = (const int*)  d_in[1];
    const float* ea  = (const float*)d_in[2];
    const float* W1  = (const float*)d_in[3];
    const float* b1  = (const float*)d_in[4];
    const float* W2  = (const float*)d_in[5];
    const float* b2  = (const float*)d_in[6];
    const float* Wfc = (const float*)d_in[7];
    const float* bfc = (const float*)d_in[8];
    float* out = (float*)d_out;
    const int* src = ei;
    const int* dst = ei + NE;

    char* ws = (char*)d_ws;
    size_t off = 0;
    unsigned long long* packed = (unsigned long long*)(ws + off); off += (size_t)N_NODES * 8;
    int*   counts = (int*)  (ws + off); off += (size_t)N_NODES * 4;
    int*   rowptr = (int*)  (ws + off); off += (size_t)N_NODES * 4;
    int*   partial= (int*)  (ws + off); off += 4096;
    float* dis    = (float*)(ws + off); off += (size_t)N_NODES * 4;
    int2*  csr    = (int2*) (ws + off); off += (size_t)NE * 8;
    unsigned short* xb = (unsigned short*)(ws + off); off += (size_t)N_NODES * CIN * 2;
    float* h1     = (float*)(ws + off); off += (size_t)N_NODES * H2X * 4;
    unsigned short* t2b = (unsigned short*)(ws + off); off += (size_t)N_NODES * HID * 2;
    float* h2     = (float*)h1;         // h1 dead after k_gemm2; reuse
    int*   pos    = (int*)h1;           // pos dead before h1 is written; alias

    // zero the packed histogram only
    hipMemsetAsync(packed, 0, (size_t)N_NODES * 8, stream);

    k_pass1<<<NE / 256, 256, 0, stream>>>(dst, ea, packed, pos);
    k_xcast<<<(N_NODES * CIN / 4) / 256, 256, 0, stream>>>(x, xb);
    k_dis<<<N_NODES / 256, 256, 0, stream>>>(packed, dis, counts);
    k_scan1<<<256, 256, 0, stream>>>(counts, rowptr, partial);
    k_scan2<<<1, 256, 0, stream>>>(partial);
    k_scan3<<<N_NODES / 256, 256, 0, stream>>>(rowptr, partial);
    k_edge_csr<<<NE / 256, 256, 0, stream>>>(src, dst, ea, dis, rowptr, pos, csr);
    k_layer1<<<N_NODES / 32, 256, 0, stream>>>(xb, csr, rowptr, counts, dis, W1, b1, h1);
    k_gemm2<<<N_NODES / 32, 256, 0, stream>>>(h1, W2, t2b);
    k_agg2<<<N_NODES / 32, 256, 0, stream>>>(t2b, csr, rowptr, counts, dis, b2, h2);
    k_fc<<<NGRAPH, 256, 0, stream>>>(h2, Wfc, bfc, out);
}

// Round 4
// 369.784 us; speedup vs baseline: 1.7966x; 1.2547x over previous
//
#include <hip/hip_runtime.h>

#define N_NODES 131072
#define NE      2097152
#define CIN     64
#define HID     64
#define H2X     128   // 2*HID
#define NODESG  128   // nodes per graph
#define NGRAPH  1024
#define NCLS    4

#define NBUCK   256   // buckets = dst>>9
#define NPB     512   // nodes per bucket
#define HBLK    1024  // histogram blocks
#define EPB     2048  // edges per histogram/scatter block
#define DEGSC   1048576.0f   // 2^20 fixed-point for LDS deg accumulation

// bf16 helpers (RNE; inputs finite)
__device__ __forceinline__ unsigned short f2b(float f) {
    unsigned int u = __float_as_uint(f);
    return (unsigned short)((u + 0x7fffu + ((u >> 16) & 1u)) >> 16);
}
__device__ __forceinline__ float b2f(unsigned short b) {
    return __uint_as_float((unsigned int)b << 16);
}
__device__ __forceinline__ unsigned int pack2(float a, float b) {
    return (unsigned int)f2b(a) | ((unsigned int)f2b(b) << 16);
}

// ---------------- bucketed counting sort (no global atomics) ----------------

// per-block LDS histogram over 256 coarse buckets
__global__ __launch_bounds__(256) void k_hist(const int* __restrict__ dst,
                                              int* __restrict__ hist) {
    __shared__ unsigned bh[NBUCK];
    int t = threadIdx.x;
    bh[t] = 0;
    __syncthreads();
    int base = blockIdx.x * EPB;
    #pragma unroll
    for (int k = 0; k < EPB / 256; ++k) {
        int d = dst[base + t + 256 * k];
        atomicAdd(&bh[d >> 9], 1u);
    }
    __syncthreads();
    hist[t * HBLK + blockIdx.x] = (int)bh[t];   // bucket-major layout
}

// exclusive scan (in-place capable), 512 elements per block
__global__ void k_scan1(const int* __restrict__ in, int* __restrict__ out,
                        int* __restrict__ partial) {
    __shared__ int sd[256];
    int t = threadIdx.x;
    int base = blockIdx.x * 512;
    int c0 = in[base + 2*t];
    int c1 = in[base + 2*t + 1];
    int loc = c0 + c1;
    sd[t] = loc;
    __syncthreads();
    for (int off = 1; off < 256; off <<= 1) {
        int v = (t >= off) ? sd[t - off] : 0;
        __syncthreads();
        sd[t] += v;
        __syncthreads();
    }
    int excl = sd[t] - loc;
    out[base + 2*t]     = excl;
    out[base + 2*t + 1] = excl + c0;
    if (t == 255) partial[blockIdx.x] = sd[t];
}

// scan 512 partials with 256 threads
__global__ void k_scan2(int* __restrict__ partial) {
    __shared__ int sd[256];
    int t = threadIdx.x;
    int p0 = partial[2*t], p1 = partial[2*t + 1];
    int loc = p0 + p1;
    sd[t] = loc;
    __syncthreads();
    for (int off = 1; off < 256; off <<= 1) {
        int v = (t >= off) ? sd[t - off] : 0;
        __syncthreads();
        sd[t] += v;
        __syncthreads();
    }
    int excl = sd[t] - loc;
    partial[2*t]     = excl;
    partial[2*t + 1] = excl + p0;
}

__global__ void k_scan3(int* __restrict__ data, const int* __restrict__ partial) {
    int i = blockIdx.x * blockDim.x + threadIdx.x;  // grid covers NBUCK*HBLK
    data[i] += partial[i >> 9];
}

// scatter edges into bucket-major order; cursors block-local in LDS
__global__ __launch_bounds__(256) void k_scatter(
        const int* __restrict__ src, const int* __restrict__ dst,
        const float* __restrict__ ew, const int* __restrict__ hist,
        unsigned long long* __restrict__ part) {
    __shared__ unsigned lcur[NBUCK];
    int t = threadIdx.x;
    lcur[t] = (unsigned)hist[t * HBLK + blockIdx.x];
    __syncthreads();
    int base = blockIdx.x * EPB;
    #pragma unroll
    for (int k = 0; k < EPB / 256; ++k) {
        int e = base + t + 256 * k;
        int s = src[e], d = dst[e];
        unsigned w = __float_as_uint(ew[e]);
        unsigned p = atomicAdd(&lcur[d >> 9], 1u);
        part[p] = ((unsigned long long)w << 32) |
                  ((unsigned long long)(unsigned)(d & 511) << 17) |
                  (unsigned long long)(unsigned)s;
    }
}

// one block per bucket: LDS count+deg, LDS scan -> rowptr, LDS-rank CSR scatter
__global__ __launch_bounds__(256) void k_bucket(
        const unsigned long long* __restrict__ part, const int* __restrict__ hist,
        int2* __restrict__ csr, int* __restrict__ rowptr,
        int* __restrict__ counts, float* __restrict__ dis) {
    __shared__ unsigned cnt[NPB];
    __shared__ unsigned degfx[NPB];
    __shared__ int rp[NPB];
    __shared__ int sd[256];
    int t = threadIdx.x, b = blockIdx.x;
    cnt[t] = 0; cnt[t + 256] = 0;
    degfx[t] = 0; degfx[t + 256] = 0;
    __syncthreads();
    int start = hist[b * HBLK];
    int end   = (b == NBUCK - 1) ? NE : hist[(b + 1) * HBLK];

    for (int j = start + t; j < end; j += 256) {
        unsigned long long p = part[j];
        unsigned dl = (unsigned)(p >> 17) & 511u;
        float w = __uint_as_float((unsigned)(p >> 32));
        atomicAdd(&cnt[dl], 1u);
        atomicAdd(&degfx[dl], (unsigned)(w * DEGSC));
    }
    __syncthreads();

    int c0 = (int)cnt[2*t], c1 = (int)cnt[2*t + 1];
    int loc = c0 + c1;
    sd[t] = loc;
    __syncthreads();
    for (int off = 1; off < 256; off <<= 1) {
        int v = (t >= off) ? sd[t - off] : 0;
        __syncthreads();
        sd[t] += v;
        __syncthreads();
    }
    int excl = sd[t] - loc;
    rp[2*t] = excl; rp[2*t + 1] = excl + c0;

    int n0 = b * NPB;
    rowptr[n0 + 2*t]     = start + excl;
    rowptr[n0 + 2*t + 1] = start + excl + c0;
    counts[n0 + 2*t]     = c0;
    counts[n0 + 2*t + 1] = c1;
    float dg0 = (float)degfx[2*t]     * (1.0f / DEGSC);
    float dg1 = (float)degfx[2*t + 1] * (1.0f / DEGSC);
    dis[n0 + 2*t]     = rsqrtf(dg0 + 1.0f);
    dis[n0 + 2*t + 1] = rsqrtf(dg1 + 1.0f);
    cnt[t] = 0; cnt[t + 256] = 0;
    __syncthreads();

    for (int j = start + t; j < end; j += 256) {
        unsigned long long p = part[j];
        unsigned dl = (unsigned)(p >> 17) & 511u;
        int s = (int)(p & 0x1ffffu);
        unsigned r = atomicAdd(&cnt[dl], 1u);
        csr[start + rp[dl] + (int)r] = make_int2(s, (int)(unsigned)(p >> 32));
    }
}

// csr.y: ew -> dis[src]*ew  (dis[dst] factored out; applied per-node in agg)
__global__ void k_fix(int2* __restrict__ csr, const float* __restrict__ dis) {
    int e = blockIdx.x * blockDim.x + threadIdx.x;
    if (e < NE) {
        int2 p = csr[e];
        float f = dis[p.x] * __uint_as_float((unsigned)p.y);
        csr[e] = make_int2(p.x, __float_as_int(f));
    }
}

// x -> bf16 table (4 floats / thread)
__global__ void k_xcast(const float* __restrict__ x, unsigned short* __restrict__ xb) {
    int i = blockIdx.x * blockDim.x + threadIdx.x;
    float4 v = ((const float4*)x)[i];
    ((uint2*)xb)[i] = make_uint2(pack2(v.x, v.y), pack2(v.z, v.w));
}

// ---------------- layer 1: h1 = relu( (A_hat xb) @ W1 + b1 ) ----------------

__global__ __launch_bounds__(256, 6) void k_layer1(
        const unsigned short* __restrict__ xb, const int2* __restrict__ csr,
        const int* __restrict__ rowptr, const int* __restrict__ counts,
        const float* __restrict__ dis, const float* __restrict__ W1,
        const float* __restrict__ b1, float* __restrict__ h1) {
    __shared__ unsigned int sWb[CIN * H2X / 2];   // 16 KB bf16 pairs
    __shared__ float sb[H2X];
    __shared__ float sagg[32][CIN + 1];
    int tid = threadIdx.x;

    const float4* W4 = (const float4*)W1;
    #pragma unroll
    for (int k = 0; k < 8; ++k) {
        float4 v = W4[tid + 256*k];
        ((uint2*)sWb)[tid + 256*k] = make_uint2(pack2(v.x, v.y), pack2(v.z, v.w));
    }
    if (tid < H2X) sb[tid] = b1[tid];

    int wave = tid >> 6, lane = tid & 63;
    int n0 = blockIdx.x * 32;

    for (int i = 0; i < 8; ++i) {
        int m = wave * 8 + i;
        int n = n0 + m;
        float dn = dis[n];
        int rs = rowptr[n], cnt = counts[n];
        float acc = dn * b2f(xb[((unsigned)n << 6) | lane]);   // self-loop (dn applied at end)
        int cm = cnt < 64 ? cnt : 64;
        int2 myp = (lane < cm) ? csr[rs + lane] : make_int2(0, 0);
        int j = 0;
        for (; j + 8 <= cm; j += 8) {
            int s[8]; float f[8], v[8];
            #pragma unroll
            for (int q = 0; q < 8; ++q) {
                s[q] = __shfl(myp.x, j + q);
                f[q] = __int_as_float(__shfl(myp.y, j + q));
            }
            #pragma unroll
            for (int q = 0; q < 8; ++q) v[q] = b2f(xb[((unsigned)s[q] << 6) | lane]);
            #pragma unroll
            for (int q = 0; q < 8; ++q) acc = fmaf(f[q], v[q], acc);
        }
        for (; j + 4 <= cm; j += 4) {
            int s[4]; float f[4], v[4];
            #pragma unroll
            for (int q = 0; q < 4; ++q) {
                s[q] = __shfl(myp.x, j + q);
                f[q] = __int_as_float(__shfl(myp.y, j + q));
            }
            #pragma unroll
            for (int q = 0; q < 4; ++q) v[q] = b2f(xb[((unsigned)s[q] << 6) | lane]);
            #pragma unroll
            for (int q = 0; q < 4; ++q) acc = fmaf(f[q], v[q], acc);
        }
        for (; j < cm; ++j) {
            int s = __shfl(myp.x, j);
            float f = __int_as_float(__shfl(myp.y, j));
            acc = fmaf(f, b2f(xb[((unsigned)s << 6) | lane]), acc);
        }
        for (int jj = 64; jj < cnt; ++jj) {
            int2 p = csr[rs + jj];
            acc = fmaf(__int_as_float(p.y), b2f(xb[((unsigned)p.x << 6) | lane]), acc);
        }
        sagg[m][lane] = dn * acc;
    }
    __syncthreads();

    int ot = tid & 31, mt = tid >> 5;
    int o0 = ot * 4, m0 = mt * 4;
    float accr[4][4] = {};
    #pragma unroll 8
    for (int cc = 0; cc < CIN; ++cc) {
        uint2 wu = ((const uint2*)sWb)[cc * 32 + ot];
        float w0 = __uint_as_float(wu.x << 16);
        float w1 = __uint_as_float(wu.x & 0xffff0000u);
        float w2 = __uint_as_float(wu.y << 16);
        float w3 = __uint_as_float(wu.y & 0xffff0000u);
        float a0 = sagg[m0 + 0][cc];
        float a1 = sagg[m0 + 1][cc];
        float a2 = sagg[m0 + 2][cc];
        float a3 = sagg[m0 + 3][cc];
        accr[0][0] = fmaf(a0, w0, accr[0][0]); accr[0][1] = fmaf(a0, w1, accr[0][1]);
        accr[0][2] = fmaf(a0, w2, accr[0][2]); accr[0][3] = fmaf(a0, w3, accr[0][3]);
        accr[1][0] = fmaf(a1, w0, accr[1][0]); accr[1][1] = fmaf(a1, w1, accr[1][1]);
        accr[1][2] = fmaf(a1, w2, accr[1][2]); accr[1][3] = fmaf(a1, w3, accr[1][3]);
        accr[2][0] = fmaf(a2, w0, accr[2][0]); accr[2][1] = fmaf(a2, w1, accr[2][1]);
        accr[2][2] = fmaf(a2, w2, accr[2][2]); accr[2][3] = fmaf(a2, w3, accr[2][3]);
        accr[3][0] = fmaf(a3, w0, accr[3][0]); accr[3][1] = fmaf(a3, w1, accr[3][1]);
        accr[3][2] = fmaf(a3, w2, accr[3][2]); accr[3][3] = fmaf(a3, w3, accr[3][3]);
    }
    #pragma unroll
    for (int i2 = 0; i2 < 4; ++i2) {
        float4 o;
        o.x = fmaxf(accr[i2][0] + sb[o0 + 0], 0.f);
        o.y = fmaxf(accr[i2][1] + sb[o0 + 1], 0.f);
        o.z = fmaxf(accr[i2][2] + sb[o0 + 2], 0.f);
        o.w = fmaxf(accr[i2][3] + sb[o0 + 3], 0.f);
        *(float4*)&h1[(size_t)(n0 + m0 + i2) * H2X + o0] = o;
    }
}

// ---------------- layer 2 GEMM: t2b = bf16( h1 @ W2 ) ----------------

__global__ __launch_bounds__(256) void k_gemm2(
        const float* __restrict__ h1, const float* __restrict__ W2,
        unsigned short* __restrict__ t2b) {
    __shared__ float sW[H2X * HID];        // 32 KB
    __shared__ float sh[32][H2X + 4];      // 16.9 KB
    int tid = threadIdx.x;

    const float4* W4 = (const float4*)W2;
    float4* sW4 = (float4*)sW;
    #pragma unroll
    for (int k = 0; k < 8; ++k) sW4[tid + 256*k] = W4[tid + 256*k];

    int n0 = blockIdx.x * 32;
    #pragma unroll
    for (int k = 0; k < 4; ++k) {
        int idx = tid + 256 * k;
        int r = idx >> 5;
        int c4 = idx & 31;
        float4 v = *(const float4*)&h1[(size_t)(n0 + r) * H2X + c4 * 4];
        *(float4*)&sh[r][c4 * 4] = v;
    }
    __syncthreads();

    int ot = tid & 15, mt = tid >> 4;
    int o0 = ot * 4, m0 = mt * 2;
    float accr[2][4] = {};
    #pragma unroll 8
    for (int cc = 0; cc < H2X; ++cc) {
        float4 w4 = *(const float4*)&sW[cc * HID + o0];
        float a0 = sh[m0][cc];
        float a1 = sh[m0 + 1][cc];
        accr[0][0] = fmaf(a0, w4.x, accr[0][0]); accr[0][1] = fmaf(a0, w4.y, accr[0][1]);
        accr[0][2] = fmaf(a0, w4.z, accr[0][2]); accr[0][3] = fmaf(a0, w4.w, accr[0][3]);
        accr[1][0] = fmaf(a1, w4.x, accr[1][0]); accr[1][1] = fmaf(a1, w4.y, accr[1][1]);
        accr[1][2] = fmaf(a1, w4.z, accr[1][2]); accr[1][3] = fmaf(a1, w4.w, accr[1][3]);
    }
    #pragma unroll
    for (int i2 = 0; i2 < 2; ++i2) {
        unsigned int a = pack2(accr[i2][0], accr[i2][1]);
        unsigned int b = pack2(accr[i2][2], accr[i2][3]);
        ((uint2*)t2b)[(size_t)(n0 + m0 + i2) * (HID/4) + (o0 >> 2)] = make_uint2(a, b);
    }
}

// ---------------- layer 2 aggregation: h2 = relu(A_hat t2b + b2) ----------------

__global__ __launch_bounds__(256) void k_agg2(
        const unsigned short* __restrict__ t2b, const int2* __restrict__ csr,
        const int* __restrict__ rowptr, const int* __restrict__ counts,
        const float* __restrict__ dis, const float* __restrict__ b2,
        float* __restrict__ h2) {
    int tid = threadIdx.x;
    int wave = tid >> 6, lane = tid & 63;
    int n0 = blockIdx.x * 32;
    float bb = b2[lane];
    for (int i = 0; i < 8; ++i) {
        int n = n0 + wave * 8 + i;
        float dn = dis[n];
        int rs = rowptr[n], cnt = counts[n];
        float acc = dn * b2f(t2b[((unsigned)n << 6) | lane]);
        int cm = cnt < 64 ? cnt : 64;
        int2 myp = (lane < cm) ? csr[rs + lane] : make_int2(0, 0);
        int j = 0;
        for (; j + 8 <= cm; j += 8) {
            int s[8]; float f[8], v[8];
            #pragma unroll
            for (int q = 0; q < 8; ++q) {
                s[q] = __shfl(myp.x, j + q);
                f[q] = __int_as_float(__shfl(myp.y, j + q));
            }
            #pragma unroll
            for (int q = 0; q < 8; ++q) v[q] = b2f(t2b[((unsigned)s[q] << 6) | lane]);
            #pragma unroll
            for (int q = 0; q < 8; ++q) acc = fmaf(f[q], v[q], acc);
        }
        for (; j + 4 <= cm; j += 4) {
            int s[4]; float f[4], v[4];
            #pragma unroll
            for (int q = 0; q < 4; ++q) {
                s[q] = __shfl(myp.x, j + q);
                f[q] = __int_as_float(__shfl(myp.y, j + q));
            }
            #pragma unroll
            for (int q = 0; q < 4; ++q) v[q] = b2f(t2b[((unsigned)s[q] << 6) | lane]);
            #pragma unroll
            for (int q = 0; q < 4; ++q) acc = fmaf(f[q], v[q], acc);
        }
        for (; j < cm; ++j) {
            int s = __shfl(myp.x, j);
            float f = __int_as_float(__shfl(myp.y, j));
            acc = fmaf(f, b2f(t2b[((unsigned)s << 6) | lane]), acc);
        }
        for (int jj = 64; jj < cnt; ++jj) {
            int2 p = csr[rs + jj];
            acc = fmaf(__int_as_float(p.y), b2f(t2b[((unsigned)p.x << 6) | lane]), acc);
        }
        h2[((unsigned)n << 6) | lane] = fmaxf(dn * acc + bb, 0.f);
    }
}

// ---------------- FC + softmax ----------------

__global__ __launch_bounds__(256) void k_fc(
        const float* __restrict__ h2, const float* __restrict__ Wfc,
        const float* __restrict__ bfc, float* __restrict__ out) {
    __shared__ float4 red[256];
    int b = blockIdx.x, t = threadIdx.x;
    const float* hrow = h2 + (size_t)b * (HID * NODESG);
    const float4* W4 = (const float4*)Wfc;
    float4 a = make_float4(0.f, 0.f, 0.f, 0.f);
    #pragma unroll 4
    for (int j = 0; j < 32; ++j) {
        int i = j * 256 + t;
        float hv = hrow[i];
        float4 w = W4[i];
        a.x = fmaf(hv, w.x, a.x);
        a.y = fmaf(hv, w.y, a.y);
        a.z = fmaf(hv, w.z, a.z);
        a.w = fmaf(hv, w.w, a.w);
    }
    red[t] = a;
    __syncthreads();
    for (int s = 128; s > 0; s >>= 1) {
        if (t < s) {
            red[t].x += red[t + s].x; red[t].y += red[t + s].y;
            red[t].z += red[t + s].z; red[t].w += red[t + s].w;
        }
        __syncthreads();
    }
    if (t == 0) {
        float l0 = red[0].x + bfc[0];
        float l1 = red[0].y + bfc[1];
        float l2 = red[0].z + bfc[2];
        float l3 = red[0].w + bfc[3];
        float mx = fmaxf(fmaxf(l0, l1), fmaxf(l2, l3));
        float e0 = expf(l0 - mx), e1 = expf(l1 - mx);
        float e2 = expf(l2 - mx), e3 = expf(l3 - mx);
        float inv = 1.f / (e0 + e1 + e2 + e3);
        float4 o = make_float4(e0 * inv, e1 * inv, e2 * inv, e3 * inv);
        *(float4*)&out[(size_t)b * 4] = o;
    }
}

// ---------------- launch ----------------

extern "C" void kernel_launch(void* const* d_in, const int* in_sizes, int n_in,
                              void* d_out, int out_size, void* d_ws, size_t ws_size,
                              hipStream_t stream) {
    const float* x   = (const float*)d_in[0];
    const int*   ei  = (const int*)  d_in[1];
    const float* ea  = (const float*)d_in[2];
    const float* W1  = (const float*)d_in[3];
    const float* b1  = (const float*)d_in[4];
    const float* W2  = (const float*)d_in[5];
    const float* b2  = (const float*)d_in[6];
    const float* Wfc = (const float*)d_in[7];
    const float* bfc = (const float*)d_in[8];
    float* out = (float*)d_out;
    const int* src = ei;
    const int* dst = ei + NE;

    char* ws = (char*)d_ws;
    size_t off = 0;
    int*   hist   = (int*)  (ws + off); off += (size_t)NBUCK * HBLK * 4;  // 1 MB
    int*   partial= (int*)  (ws + off); off += 4096;
    int*   counts = (int*)  (ws + off); off += (size_t)N_NODES * 4;
    int*   rowptr = (int*)  (ws + off); off += (size_t)N_NODES * 4;
    float* dis    = (float*)(ws + off); off += (size_t)N_NODES * 4;
    int2*  csr    = (int2*) (ws + off); off += (size_t)NE * 8;
    unsigned short* xb = (unsigned short*)(ws + off); off += (size_t)N_NODES * CIN * 2;
    float* h1     = (float*)(ws + off); off += (size_t)N_NODES * H2X * 4;
    unsigned short* t2b = (unsigned short*)(ws + off); off += (size_t)N_NODES * HID * 2;
    float* h2     = (float*)h1;                        // h1 dead after k_gemm2
    unsigned long long* part = (unsigned long long*)h1; // dead before h1 written

    hipMemsetAsync(hist, 0, (size_t)NBUCK * HBLK * 4, stream);

    k_hist   <<<HBLK, 256, 0, stream>>>(dst, hist);
    k_xcast  <<<(N_NODES * CIN / 4) / 256, 256, 0, stream>>>(x, xb);
    k_scan1  <<<NBUCK * HBLK / 512, 256, 0, stream>>>(hist, hist, partial);
    k_scan2  <<<1, 256, 0, stream>>>(partial);
    k_scan3  <<<NBUCK * HBLK / 256, 256, 0, stream>>>(hist, partial);
    k_scatter<<<HBLK, 256, 0, stream>>>(src, dst, ea, hist, part);
    k_bucket <<<NBUCK, 256, 0, stream>>>(part, hist, csr, rowptr, counts, dis);
    k_fix    <<<NE / 256, 256, 0, stream>>>(csr, dis);
    k_layer1 <<<N_NODES / 32, 256, 0, stream>>>(xb, csr, rowptr, counts, dis, W1, b1, h1);
    k_gemm2  <<<N_NODES / 32, 256, 0, stream>>>(h1, W2, t2b);
    k_agg2   <<<N_NODES / 32, 256, 0, stream>>>(t2b, csr, rowptr, counts, dis, b2, h2);
    k_fc     <<<NGRAPH, 256, 0, stream>>>(h2, Wfc, bfc, out);
}

// Round 5
// 349.485 us; speedup vs baseline: 1.9009x; 1.0581x over previous
//
#include <hip/hip_runtime.h>

#define N_NODES 131072
#define NE      2097152
#define CIN     64
#define HID     64
#define H2X     128   // 2*HID
#define NODESG  128   // nodes per graph
#define NGRAPH  1024
#define NCLS    4

#define NBUCK   256   // buckets = dst>>9
#define NPB     512   // nodes per bucket
#define HBLK    1024  // histogram blocks
#define EPB     2048  // edges per histogram/scatter block
#define DEGSC   1048576.0f   // 2^20 fixed-point for LDS deg accumulation

// bf16 helpers (RNE; inputs finite)
__device__ __forceinline__ unsigned short f2b(float f) {
    unsigned int u = __float_as_uint(f);
    return (unsigned short)((u + 0x7fffu + ((u >> 16) & 1u)) >> 16);
}
__device__ __forceinline__ float b2f(unsigned short b) {
    return __uint_as_float((unsigned int)b << 16);
}
__device__ __forceinline__ unsigned int pack2(float a, float b) {
    return (unsigned int)f2b(a) | ((unsigned int)f2b(b) << 16);
}
__device__ __forceinline__ float blo(unsigned u) { return __uint_as_float(u << 16); }
__device__ __forceinline__ float bhi(unsigned u) { return __uint_as_float(u & 0xffff0000u); }

// ---------------- bucketed counting sort (no global atomics) ----------------

__global__ __launch_bounds__(256) void k_hist(const int* __restrict__ dst,
                                              int* __restrict__ hist) {
    __shared__ unsigned bh[NBUCK];
    int t = threadIdx.x;
    bh[t] = 0;
    __syncthreads();
    int base = blockIdx.x * EPB;
    #pragma unroll
    for (int k = 0; k < EPB / 256; ++k) {
        int d = dst[base + t + 256 * k];
        atomicAdd(&bh[d >> 9], 1u);
    }
    __syncthreads();
    hist[t * HBLK + blockIdx.x] = (int)bh[t];   // bucket-major layout
}

__global__ void k_scan1(const int* __restrict__ in, int* __restrict__ out,
                        int* __restrict__ partial) {
    __shared__ int sd[256];
    int t = threadIdx.x;
    int base = blockIdx.x * 512;
    int c0 = in[base + 2*t];
    int c1 = in[base + 2*t + 1];
    int loc = c0 + c1;
    sd[t] = loc;
    __syncthreads();
    for (int off = 1; off < 256; off <<= 1) {
        int v = (t >= off) ? sd[t - off] : 0;
        __syncthreads();
        sd[t] += v;
        __syncthreads();
    }
    int excl = sd[t] - loc;
    out[base + 2*t]     = excl;
    out[base + 2*t + 1] = excl + c0;
    if (t == 255) partial[blockIdx.x] = sd[t];
}

__global__ void k_scan2(int* __restrict__ partial) {
    __shared__ int sd[256];
    int t = threadIdx.x;
    int p0 = partial[2*t], p1 = partial[2*t + 1];
    int loc = p0 + p1;
    sd[t] = loc;
    __syncthreads();
    for (int off = 1; off < 256; off <<= 1) {
        int v = (t >= off) ? sd[t - off] : 0;
        __syncthreads();
        sd[t] += v;
        __syncthreads();
    }
    int excl = sd[t] - loc;
    partial[2*t]     = excl;
    partial[2*t + 1] = excl + p0;
}

__global__ void k_scan3(int* __restrict__ data, const int* __restrict__ partial) {
    int i = blockIdx.x * blockDim.x + threadIdx.x;
    data[i] += partial[i >> 9];
}

__global__ __launch_bounds__(256) void k_scatter(
        const int* __restrict__ src, const int* __restrict__ dst,
        const float* __restrict__ ew, const int* __restrict__ hist,
        unsigned long long* __restrict__ part) {
    __shared__ unsigned lcur[NBUCK];
    int t = threadIdx.x;
    lcur[t] = (unsigned)hist[t * HBLK + blockIdx.x];
    __syncthreads();
    int base = blockIdx.x * EPB;
    #pragma unroll
    for (int k = 0; k < EPB / 256; ++k) {
        int e = base + t + 256 * k;
        int s = src[e], d = dst[e];
        unsigned w = __float_as_uint(ew[e]);
        unsigned p = atomicAdd(&lcur[d >> 9], 1u);
        part[p] = ((unsigned long long)w << 32) |
                  ((unsigned long long)(unsigned)(d & 511) << 17) |
                  (unsigned long long)(unsigned)s;
    }
}

// one block per bucket: LDS count+deg, LDS scan -> rowptr, LDS-rank CSR scatter
__global__ __launch_bounds__(256) void k_bucket(
        const unsigned long long* __restrict__ part, const int* __restrict__ hist,
        int2* __restrict__ csr, int* __restrict__ rowptr,
        int* __restrict__ counts, float* __restrict__ dis) {
    __shared__ unsigned cnt[NPB];
    __shared__ unsigned degfx[NPB];
    __shared__ int rp[NPB];
    __shared__ int sd[256];
    int t = threadIdx.x, b = blockIdx.x;
    cnt[t] = 0; cnt[t + 256] = 0;
    degfx[t] = 0; degfx[t + 256] = 0;
    __syncthreads();
    int start = hist[b * HBLK];
    int end   = (b == NBUCK - 1) ? NE : hist[(b + 1) * HBLK];

    for (int j = start + t; j < end; j += 256) {
        unsigned long long p = part[j];
        unsigned dl = (unsigned)(p >> 17) & 511u;
        float w = __uint_as_float((unsigned)(p >> 32));
        atomicAdd(&cnt[dl], 1u);
        atomicAdd(&degfx[dl], (unsigned)(w * DEGSC));
    }
    __syncthreads();

    int c0 = (int)cnt[2*t], c1 = (int)cnt[2*t + 1];
    int loc = c0 + c1;
    sd[t] = loc;
    __syncthreads();
    for (int off = 1; off < 256; off <<= 1) {
        int v = (t >= off) ? sd[t - off] : 0;
        __syncthreads();
        sd[t] += v;
        __syncthreads();
    }
    int excl = sd[t] - loc;
    rp[2*t] = excl; rp[2*t + 1] = excl + c0;

    int n0 = b * NPB;
    rowptr[n0 + 2*t]     = start + excl;
    rowptr[n0 + 2*t + 1] = start + excl + c0;
    counts[n0 + 2*t]     = c0;
    counts[n0 + 2*t + 1] = c1;
    float dg0 = (float)degfx[2*t]     * (1.0f / DEGSC);
    float dg1 = (float)degfx[2*t + 1] * (1.0f / DEGSC);
    dis[n0 + 2*t]     = rsqrtf(dg0 + 1.0f);
    dis[n0 + 2*t + 1] = rsqrtf(dg1 + 1.0f);
    cnt[t] = 0; cnt[t + 256] = 0;
    __syncthreads();

    for (int j = start + t; j < end; j += 256) {
        unsigned long long p = part[j];
        unsigned dl = (unsigned)(p >> 17) & 511u;
        int s = (int)(p & 0x1ffffu);
        unsigned r = atomicAdd(&cnt[dl], 1u);
        csr[start + rp[dl] + (int)r] = make_int2(s, (int)(unsigned)(p >> 32)); // raw ew
    }
}

// y = bf16( dis[node] * x )  (prescaled gather table)
__global__ void k_xcast(const float* __restrict__ x, const float* __restrict__ dis,
                        uint2* __restrict__ xb2) {
    int i = blockIdx.x * blockDim.x + threadIdx.x;   // over N*CIN/4
    float d = dis[i >> 4];
    float4 v = ((const float4*)x)[i];
    xb2[i] = make_uint2(pack2(d * v.x, d * v.y), pack2(d * v.z, d * v.w));
}

// ---------------- layer 1: h1 = relu( (A_hat x) @ W1 + b1 ) ----------------
// quarter-wave edge parallelism: 16 lanes/edge, 4 ch/lane (uint2 = 4 bf16)

__global__ __launch_bounds__(256, 6) void k_layer1(
        const uint2* __restrict__ xb2, const int2* __restrict__ csr,
        const int* __restrict__ rowptr, const int* __restrict__ counts,
        const float* __restrict__ dis, const float* __restrict__ W1,
        const float* __restrict__ b1, float* __restrict__ h1) {
    __shared__ unsigned int sWb[CIN * H2X / 2];   // 16 KB bf16 pairs
    __shared__ float sb[H2X];
    __shared__ float sagg[32][CIN + 1];           // stride 65: conflict-free GEMM reads
    int tid = threadIdx.x;

    const float4* W4 = (const float4*)W1;
    #pragma unroll
    for (int k = 0; k < 8; ++k) {
        float4 v = W4[tid + 256*k];
        ((uint2*)sWb)[tid + 256*k] = make_uint2(pack2(v.x, v.y), pack2(v.z, v.w));
    }
    if (tid < H2X) sb[tid] = b1[tid];

    int wave = tid >> 6, lane = tid & 63;
    int qid = lane >> 4, ql = lane & 15;
    int n0 = blockIdx.x * 32;

    for (int i = 0; i < 8; ++i) {
        int m = wave * 8 + i;
        int n = n0 + m;
        float dn = dis[n];
        int rs = rowptr[n], cnt = counts[n];
        int cm = cnt < 64 ? cnt : 64;
        int2 myp = (lane < cm) ? csr[rs + lane] : make_int2(0, 0);
        float a0 = 0.f, a1 = 0.f, a2 = 0.f, a3 = 0.f;
        int steps = (cm + 3) >> 2;      // quarter qid handles edges 4k+qid (f=0 pads)
        int j = qid, k = 0;
        for (; k + 4 <= steps; k += 4) {
            int   sA = __shfl(myp.x, j);      float fA = __int_as_float(__shfl(myp.y, j));
            int   sB = __shfl(myp.x, j + 4);  float fB = __int_as_float(__shfl(myp.y, j + 4));
            int   sC = __shfl(myp.x, j + 8);  float fC = __int_as_float(__shfl(myp.y, j + 8));
            int   sD = __shfl(myp.x, j + 12); float fD = __int_as_float(__shfl(myp.y, j + 12));
            uint2 vA = xb2[((unsigned)sA << 4) | ql];
            uint2 vB = xb2[((unsigned)sB << 4) | ql];
            uint2 vC = xb2[((unsigned)sC << 4) | ql];
            uint2 vD = xb2[((unsigned)sD << 4) | ql];
            a0 = fmaf(fA, blo(vA.x), a0); a1 = fmaf(fA, bhi(vA.x), a1);
            a2 = fmaf(fA, blo(vA.y), a2); a3 = fmaf(fA, bhi(vA.y), a3);
            a0 = fmaf(fB, blo(vB.x), a0); a1 = fmaf(fB, bhi(vB.x), a1);
            a2 = fmaf(fB, blo(vB.y), a2); a3 = fmaf(fB, bhi(vB.y), a3);
            a0 = fmaf(fC, blo(vC.x), a0); a1 = fmaf(fC, bhi(vC.x), a1);
            a2 = fmaf(fC, blo(vC.y), a2); a3 = fmaf(fC, bhi(vC.y), a3);
            a0 = fmaf(fD, blo(vD.x), a0); a1 = fmaf(fD, bhi(vD.x), a1);
            a2 = fmaf(fD, blo(vD.y), a2); a3 = fmaf(fD, bhi(vD.y), a3);
            j += 16;
        }
        for (; k < steps; ++k) {
            int   s = __shfl(myp.x, j);
            float f = __int_as_float(__shfl(myp.y, j));
            uint2 v = xb2[((unsigned)s << 4) | ql];
            a0 = fmaf(f, blo(v.x), a0); a1 = fmaf(f, bhi(v.x), a1);
            a2 = fmaf(f, blo(v.y), a2); a3 = fmaf(f, bhi(v.y), a3);
            j += 4;
        }
        for (int jj = 64; jj < cnt; ++jj) {   // degree >64: essentially never
            int2 p = csr[rs + jj];
            if (qid == 0) {
                float f = __int_as_float(p.y);
                uint2 v = xb2[((unsigned)p.x << 4) | ql];
                a0 = fmaf(f, blo(v.x), a0); a1 = fmaf(f, bhi(v.x), a1);
                a2 = fmaf(f, blo(v.y), a2); a3 = fmaf(f, bhi(v.y), a3);
            }
        }
        // merge quarters
        a0 += __shfl_xor(a0, 16); a1 += __shfl_xor(a1, 16);
        a2 += __shfl_xor(a2, 16); a3 += __shfl_xor(a3, 16);
        a0 += __shfl_xor(a0, 32); a1 += __shfl_xor(a1, 32);
        a2 += __shfl_xor(a2, 32); a3 += __shfl_xor(a3, 32);
        // self term (y[n]) + scale by dn
        uint2 vs = xb2[((unsigned)n << 4) | ql];
        a0 = dn * (a0 + blo(vs.x)); a1 = dn * (a1 + bhi(vs.x));
        a2 = dn * (a2 + blo(vs.y)); a3 = dn * (a3 + bhi(vs.y));
        if (qid == 0) {
            int c = ql * 4;
            sagg[m][c]     = a0; sagg[m][c + 1] = a1;
            sagg[m][c + 2] = a2; sagg[m][c + 3] = a3;
        }
    }
    __syncthreads();

    int ot = tid & 31, mt = tid >> 5;
    int o0 = ot * 4, m0 = mt * 4;
    float accr[4][4] = {};
    #pragma unroll 8
    for (int cc = 0; cc < CIN; ++cc) {
        uint2 wu = ((const uint2*)sWb)[cc * 32 + ot];
        float w0 = blo(wu.x), w1 = bhi(wu.x), w2 = blo(wu.y), w3 = bhi(wu.y);
        float a0 = sagg[m0 + 0][cc];
        float a1 = sagg[m0 + 1][cc];
        float a2 = sagg[m0 + 2][cc];
        float a3 = sagg[m0 + 3][cc];
        accr[0][0] = fmaf(a0, w0, accr[0][0]); accr[0][1] = fmaf(a0, w1, accr[0][1]);
        accr[0][2] = fmaf(a0, w2, accr[0][2]); accr[0][3] = fmaf(a0, w3, accr[0][3]);
        accr[1][0] = fmaf(a1, w0, accr[1][0]); accr[1][1] = fmaf(a1, w1, accr[1][1]);
        accr[1][2] = fmaf(a1, w2, accr[1][2]); accr[1][3] = fmaf(a1, w3, accr[1][3]);
        accr[2][0] = fmaf(a2, w0, accr[2][0]); accr[2][1] = fmaf(a2, w1, accr[2][1]);
        accr[2][2] = fmaf(a2, w2, accr[2][2]); accr[2][3] = fmaf(a2, w3, accr[2][3]);
        accr[3][0] = fmaf(a3, w0, accr[3][0]); accr[3][1] = fmaf(a3, w1, accr[3][1]);
        accr[3][2] = fmaf(a3, w2, accr[3][2]); accr[3][3] = fmaf(a3, w3, accr[3][3]);
    }
    #pragma unroll
    for (int i2 = 0; i2 < 4; ++i2) {
        float4 o;
        o.x = fmaxf(accr[i2][0] + sb[o0 + 0], 0.f);
        o.y = fmaxf(accr[i2][1] + sb[o0 + 1], 0.f);
        o.z = fmaxf(accr[i2][2] + sb[o0 + 2], 0.f);
        o.w = fmaxf(accr[i2][3] + sb[o0 + 3], 0.f);
        *(float4*)&h1[(size_t)(n0 + m0 + i2) * H2X + o0] = o;
    }
}

// ---------------- layer 2 GEMM: t2y = bf16( dis * (h1 @ W2) ) ----------------

__global__ __launch_bounds__(256) void k_gemm2(
        const float* __restrict__ h1, const float* __restrict__ W2,
        const float* __restrict__ dis, uint2* __restrict__ t2y) {
    __shared__ float sW[H2X * HID];        // 32 KB
    __shared__ float sh[32][H2X + 4];      // 16.9 KB
    int tid = threadIdx.x;

    const float4* W4 = (const float4*)W2;
    float4* sW4 = (float4*)sW;
    #pragma unroll
    for (int k = 0; k < 8; ++k) sW4[tid + 256*k] = W4[tid + 256*k];

    int n0 = blockIdx.x * 32;
    #pragma unroll
    for (int k = 0; k < 4; ++k) {
        int idx = tid + 256 * k;
        int r = idx >> 5;
        int c4 = idx & 31;
        float4 v = *(const float4*)&h1[(size_t)(n0 + r) * H2X + c4 * 4];
        *(float4*)&sh[r][c4 * 4] = v;
    }
    __syncthreads();

    int ot = tid & 15, mt = tid >> 4;
    int o0 = ot * 4, m0 = mt * 2;
    float accr[2][4] = {};
    #pragma unroll 8
    for (int cc = 0; cc < H2X; ++cc) {
        float4 w4 = *(const float4*)&sW[cc * HID + o0];
        float a0 = sh[m0][cc];
        float a1 = sh[m0 + 1][cc];
        accr[0][0] = fmaf(a0, w4.x, accr[0][0]); accr[0][1] = fmaf(a0, w4.y, accr[0][1]);
        accr[0][2] = fmaf(a0, w4.z, accr[0][2]); accr[0][3] = fmaf(a0, w4.w, accr[0][3]);
        accr[1][0] = fmaf(a1, w4.x, accr[1][0]); accr[1][1] = fmaf(a1, w4.y, accr[1][1]);
        accr[1][2] = fmaf(a1, w4.z, accr[1][2]); accr[1][3] = fmaf(a1, w4.w, accr[1][3]);
    }
    #pragma unroll
    for (int i2 = 0; i2 < 2; ++i2) {
        int n = n0 + m0 + i2;
        float dnv = dis[n];
        unsigned int a = pack2(dnv * accr[i2][0], dnv * accr[i2][1]);
        unsigned int b = pack2(dnv * accr[i2][2], dnv * accr[i2][3]);
        t2y[((size_t)n << 4) | ot] = make_uint2(a, b);
    }
}

// ---------------- layer 2 aggregation: h2 = relu( dn*(sum ew*t2y + t2y[n]) + b2 )

__global__ __launch_bounds__(256) void k_agg2(
        const uint2* __restrict__ t2y, const int2* __restrict__ csr,
        const int* __restrict__ rowptr, const int* __restrict__ counts,
        const float* __restrict__ dis, const float* __restrict__ b2,
        float* __restrict__ h2) {
    int tid = threadIdx.x;
    int wave = tid >> 6, lane = tid & 63;
    int qid = lane >> 4, ql = lane & 15;
    float4 bb = *(const float4*)&b2[ql * 4];
    int n0 = blockIdx.x * 32;
    for (int i = 0; i < 8; ++i) {
        int n = n0 + wave * 8 + i;
        float dn = dis[n];
        int rs = rowptr[n], cnt = counts[n];
        int cm = cnt < 64 ? cnt : 64;
        int2 myp = (lane < cm) ? csr[rs + lane] : make_int2(0, 0);
        float a0 = 0.f, a1 = 0.f, a2 = 0.f, a3 = 0.f;
        int steps = (cm + 3) >> 2;
        int j = qid, k = 0;
        for (; k + 4 <= steps; k += 4) {
            int   sA = __shfl(myp.x, j);      float fA = __int_as_float(__shfl(myp.y, j));
            int   sB = __shfl(myp.x, j + 4);  float fB = __int_as_float(__shfl(myp.y, j + 4));
            int   sC = __shfl(myp.x, j + 8);  float fC = __int_as_float(__shfl(myp.y, j + 8));
            int   sD = __shfl(myp.x, j + 12); float fD = __int_as_float(__shfl(myp.y, j + 12));
            uint2 vA = t2y[((unsigned)sA << 4) | ql];
            uint2 vB = t2y[((unsigned)sB << 4) | ql];
            uint2 vC = t2y[((unsigned)sC << 4) | ql];
            uint2 vD = t2y[((unsigned)sD << 4) | ql];
            a0 = fmaf(fA, blo(vA.x), a0); a1 = fmaf(fA, bhi(vA.x), a1);
            a2 = fmaf(fA, blo(vA.y), a2); a3 = fmaf(fA, bhi(vA.y), a3);
            a0 = fmaf(fB, blo(vB.x), a0); a1 = fmaf(fB, bhi(vB.x), a1);
            a2 = fmaf(fB, blo(vB.y), a2); a3 = fmaf(fB, bhi(vB.y), a3);
            a0 = fmaf(fC, blo(vC.x), a0); a1 = fmaf(fC, bhi(vC.x), a1);
            a2 = fmaf(fC, blo(vC.y), a2); a3 = fmaf(fC, bhi(vC.y), a3);
            a0 = fmaf(fD, blo(vD.x), a0); a1 = fmaf(fD, bhi(vD.x), a1);
            a2 = fmaf(fD, blo(vD.y), a2); a3 = fmaf(fD, bhi(vD.y), a3);
            j += 16;
        }
        for (; k < steps; ++k) {
            int   s = __shfl(myp.x, j);
            float f = __int_as_float(__shfl(myp.y, j));
            uint2 v = t2y[((unsigned)s << 4) | ql];
            a0 = fmaf(f, blo(v.x), a0); a1 = fmaf(f, bhi(v.x), a1);
            a2 = fmaf(f, blo(v.y), a2); a3 = fmaf(f, bhi(v.y), a3);
            j += 4;
        }
        for (int jj = 64; jj < cnt; ++jj) {
            int2 p = csr[rs + jj];
            if (qid == 0) {
                float f = __int_as_float(p.y);
                uint2 v = t2y[((unsigned)p.x << 4) | ql];
                a0 = fmaf(f, blo(v.x), a0); a1 = fmaf(f, bhi(v.x), a1);
                a2 = fmaf(f, blo(v.y), a2); a3 = fmaf(f, bhi(v.y), a3);
            }
        }
        a0 += __shfl_xor(a0, 16); a1 += __shfl_xor(a1, 16);
        a2 += __shfl_xor(a2, 16); a3 += __shfl_xor(a3, 16);
        a0 += __shfl_xor(a0, 32); a1 += __shfl_xor(a1, 32);
        a2 += __shfl_xor(a2, 32); a3 += __shfl_xor(a3, 32);
        uint2 vs = t2y[((unsigned)n << 4) | ql];
        if (qid == 0) {
            float4 o;
            o.x = fmaxf(fmaf(dn, a0 + blo(vs.x), bb.x), 0.f);
            o.y = fmaxf(fmaf(dn, a1 + bhi(vs.x), bb.y), 0.f);
            o.z = fmaxf(fmaf(dn, a2 + blo(vs.y), bb.z), 0.f);
            o.w = fmaxf(fmaf(dn, a3 + bhi(vs.y), bb.w), 0.f);
            *(float4*)&h2[(((unsigned)n << 6) | (ql * 4))] = o;
        }
    }
}

// ---------------- FC + softmax ----------------

__global__ __launch_bounds__(256) void k_fc(
        const float* __restrict__ h2, const float* __restrict__ Wfc,
        const float* __restrict__ bfc, float* __restrict__ out) {
    __shared__ float4 red[256];
    int b = blockIdx.x, t = threadIdx.x;
    const float* hrow = h2 + (size_t)b * (HID * NODESG);
    const float4* W4 = (const float4*)Wfc;
    float4 a = make_float4(0.f, 0.f, 0.f, 0.f);
    #pragma unroll 4
    for (int j = 0; j < 32; ++j) {
        int i = j * 256 + t;
        float hv = hrow[i];
        float4 w = W4[i];
        a.x = fmaf(hv, w.x, a.x);
        a.y = fmaf(hv, w.y, a.y);
        a.z = fmaf(hv, w.z, a.z);
        a.w = fmaf(hv, w.w, a.w);
    }
    red[t] = a;
    __syncthreads();
    for (int s = 128; s > 0; s >>= 1) {
        if (t < s) {
            red[t].x += red[t + s].x; red[t].y += red[t + s].y;
            red[t].z += red[t + s].z; red[t].w += red[t + s].w;
        }
        __syncthreads();
    }
    if (t == 0) {
        float l0 = red[0].x + bfc[0];
        float l1 = red[0].y + bfc[1];
        float l2 = red[0].z + bfc[2];
        float l3 = red[0].w + bfc[3];
        float mx = fmaxf(fmaxf(l0, l1), fmaxf(l2, l3));
        float e0 = expf(l0 - mx), e1 = expf(l1 - mx);
        float e2 = expf(l2 - mx), e3 = expf(l3 - mx);
        float inv = 1.f / (e0 + e1 + e2 + e3);
        float4 o = make_float4(e0 * inv, e1 * inv, e2 * inv, e3 * inv);
        *(float4*)&out[(size_t)b * 4] = o;
    }
}

// ---------------- launch ----------------

extern "C" void kernel_launch(void* const* d_in, const int* in_sizes, int n_in,
                              void* d_out, int out_size, void* d_ws, size_t ws_size,
                              hipStream_t stream) {
    const float* x   = (const float*)d_in[0];
    const int*   ei  = (const int*)  d_in[1];
    const float* ea  = (const float*)d_in[2];
    const float* W1  = (const float*)d_in[3];
    const float* b1  = (const float*)d_in[4];
    const float* W2  = (const float*)d_in[5];
    const float* b2  = (const float*)d_in[6];
    const float* Wfc = (const float*)d_in[7];
    const float* bfc = (const float*)d_in[8];
    float* out = (float*)d_out;
    const int* src = ei;
    const int* dst = ei + NE;

    char* ws = (char*)d_ws;
    size_t off = 0;
    int*   hist   = (int*)  (ws + off); off += (size_t)NBUCK * HBLK * 4;  // 1 MB
    int*   partial= (int*)  (ws + off); off += 4096;
    int*   counts = (int*)  (ws + off); off += (size_t)N_NODES * 4;
    int*   rowptr = (int*)  (ws + off); off += (size_t)N_NODES * 4;
    float* dis    = (float*)(ws + off); off += (size_t)N_NODES * 4;
    int2*  csr    = (int2*) (ws + off); off += (size_t)NE * 8;
    uint2* xb2    = (uint2*)(ws + off); off += (size_t)N_NODES * CIN * 2;
    float* h1     = (float*)(ws + off); off += (size_t)N_NODES * H2X * 4;
    uint2* t2y    = (uint2*)(ws + off); off += (size_t)N_NODES * HID * 2;
    float* h2     = (float*)h1;                        // h1 dead after k_gemm2
    unsigned long long* part = (unsigned long long*)h1; // dead before h1 written

    hipMemsetAsync(hist, 0, (size_t)NBUCK * HBLK * 4, stream);

    k_hist   <<<HBLK, 256, 0, stream>>>(dst, hist);
    k_scan1  <<<NBUCK * HBLK / 512, 256, 0, stream>>>(hist, hist, partial);
    k_scan2  <<<1, 256, 0, stream>>>(partial);
    k_scan3  <<<NBUCK * HBLK / 256, 256, 0, stream>>>(hist, partial);
    k_scatter<<<HBLK, 256, 0, stream>>>(src, dst, ea, hist, part);
    k_bucket <<<NBUCK, 256, 0, stream>>>(part, hist, csr, rowptr, counts, dis);
    k_xcast  <<<(N_NODES * CIN / 4) / 256, 256, 0, stream>>>(x, dis, xb2);
    k_layer1 <<<N_NODES / 32, 256, 0, stream>>>(xb2, csr, rowptr, counts, dis, W1, b1, h1);
    k_gemm2  <<<N_NODES / 32, 256, 0, stream>>>(h1, W2, dis, t2y);
    k_agg2   <<<N_NODES / 32, 256, 0, stream>>>(t2y, csr, rowptr, counts, dis, b2, h2);
    k_fc     <<<NGRAPH, 256, 0, stream>>>(h2, Wfc, bfc, out);
}